// Round 11
// baseline (466.659 us; speedup 1.0000x reference)
//
#include <hip/hip_runtime.h>

typedef __bf16 bf16;
typedef __bf16 v8bf __attribute__((ext_vector_type(8)));
typedef __bf16 v4bf __attribute__((ext_vector_type(4)));
typedef float v4f __attribute__((ext_vector_type(4)));

#define MFMA16(a, b, c) __builtin_amdgcn_mfma_f32_16x16x32_bf16(a, b, c, 0, 0, 0)

// NaN -> 0, clamp +-1e30. Insurance only.
__device__ __forceinline__ float sf(float x) {
  if (!(x == x)) return 0.f;
  return fminf(fmaxf(x, -1e30f), 1e30f);
}

// ---------------- guard fill (fp32 out) ----------------
__global__ __launch_bounds__(256) void fill_kernel(float* __restrict__ out, float v, int n) {
  int i = blockIdx.x * 256 + threadIdx.x;
  if (i < n) out[i] = v;
}

// ---------------- prep_all: tr (blocks 0..255) + stem weight prep + pmean zero
//                  + optional conv_cat prep (when ws has slack) ----------------
__global__ __launch_bounds__(256) void prep_all_kernel(
    const float* __restrict__ s_in, const float* __restrict__ q_in, bf16* __restrict__ xin,
    const float* __restrict__ ts_w, const float* __restrict__ tq_w,
    const float* ts_b, const float* ts_g, const float* ts_be, const float* ts_m, const float* ts_v,
    const float* tq_b, const float* tq_g, const float* tq_be, const float* tq_m, const float* tq_v,
    bf16* __restrict__ Wt01, float* __restrict__ ss01, float* __restrict__ pmean,
    const float* __restrict__ cc_w, const float* cc_g, const float* cc_be,
    const float* cc_m, const float* cc_v,
    bf16* __restrict__ Wt2, float* __restrict__ ss_cc, int do_prep2)
{
  int bx = blockIdx.x, t = threadIdx.x;
  if (bx < 256) {
    // NCHW fp32 -> NHWC bf16 transpose (coalesced reads along n)
    int nb = bx & 63, z = bx >> 6;
    const float* in = ((z >> 1) ? q_in : s_in) + (long)(z & 1) * 1048576;
    bf16* out = xin + (long)z * 1048576;
    int lane = t & 63, w = t >> 6;
    long n = (long)nb * 64 + lane;
#pragma unroll
    for (int i = 0; i < 8; ++i) {
      int c8 = w * 8 + i;
      v8bf o;
#pragma unroll
      for (int j = 0; j < 8; ++j) o[j] = (bf16)in[(long)(c8 * 8 + j) * 4096 + n];
      *(v8bf*)(out + n * 256 + c8 * 8) = o;
    }
    return;
  }
  int idx = (bx - 256) * 256 + t;
  if (idx < 589824) {
    int which = idx / 294912;
    int rem = idx - which * 294912;
    int co = rem / 2304;
    int r2 = rem - co * 2304;
    int tap = r2 >> 8;
    int ci = r2 & 255;
    const float* W = which ? tq_w : ts_w;
    Wt01[idx] = (bf16)W[(co * 256 + ci) * 9 + tap];
  } else if (idx < 590080) {
    int i = idx - 589824;
    int which = i >> 7, c = i & 127;
    float g, be, m, vv, bias;
    if (which == 0) { g=ts_g[c]; be=ts_be[c]; m=ts_m[c]; vv=ts_v[c]; bias=ts_b[c]; }
    else            { g=tq_g[c]; be=tq_be[c]; m=tq_m[c]; vv=tq_v[c]; bias=tq_b[c]; }
    float scale = g / sqrtf(vv + 1e-5f);
    ss01[which * 256 + c] = sf(scale);
    ss01[which * 256 + 128 + c] = sf((bias - m) * scale + be);
  } else if (idx < 590592) {
    pmean[idx - 590080] = 0.f;
  } else if (do_prep2) {
    int idx2 = idx - 590592;
    if (idx2 < 294912) {
      int co = idx2 / 2304;
      int r2 = idx2 - co * 2304;
      int tap = r2 >> 8;
      int ci = r2 & 255;
      Wt2[idx2] = (bf16)cc_w[(co * 256 + ci) * 9 + tap];
    } else if (idx2 < 295040) {
      int c = idx2 - 294912;
      float scale = cc_g[c] / sqrtf(cc_v[c] + 1e-5f);
      ss_cc[c] = sf(scale);
      ss_cc[128 + c] = sf(-cc_m[c] * scale + cc_be[c]);
    }
  }
}

// ---------------- prep2 fallback (after apply; over dead keyT) ----------------
__global__ __launch_bounds__(256) void prep2_kernel(
    const float* __restrict__ cc_w, const float* cc_g, const float* cc_be,
    const float* cc_m, const float* cc_v,
    bf16* __restrict__ Wt2, float* __restrict__ ss_cc)
{
  int idx = blockIdx.x * 256 + threadIdx.x;
  if (idx < 294912) {
    int co = idx / 2304;
    int r2 = idx - co * 2304;
    int tap = r2 >> 8;
    int ci = r2 & 255;
    Wt2[idx] = (bf16)cc_w[(co * 256 + ci) * 9 + tap];
  } else if (idx < 295040) {
    int c = idx - 294912;
    float scale = cc_g[c] / sqrtf(cc_v[c] + 1e-5f);
    ss_cc[c] = sf(scale);
    ss_cc[128 + c] = sf(-cc_m[c] * scale + cc_be[c]);
  }
}

// ---------------- 3x3 conv implicit GEMM over NHWC bf16 input, coalesced A staging;
// XCD-swizzled flat grid ----------
__global__ __launch_bounds__(256) void convN_kernel(
    const bf16* __restrict__ inA,
    const bf16* __restrict__ Wb, const float* __restrict__ ssb,
    void* __restrict__ out_, int mode)
{
  __shared__ bf16 As[66][40];
  __shared__ bf16 Bs[3][64][40];

  int bid = blockIdx.x;
  int xcd = bid & 7, slot = bid >> 3;
  int y, co0, tsr, b;
  if (mode == 0) {
    int z = xcd >> 1;
    tsr = z >> 1; b = z & 1;
    co0 = (xcd & 1) * 64;
    y = slot;
  } else {
    int combo = xcd >> 1;
    co0 = (combo >> 1) * 64;
    b = combo & 1;
    tsr = 0;
    y = (xcd & 1) * 32 + slot;
  }

  const bf16 *in0, *in1;
  const bf16* W;
  const float* sp;
  if (mode == 0) {
    in0 = inA + (long)(tsr * 2 + b) * 1048576;  // [4096][256]
    in1 = nullptr;
    W = Wb + (long)tsr * 294912;
    sp = ssb + tsr * 256;
  } else {
    in0 = inA + (long)(2 + b) * 524288; // E_q bf16 [4096][128]
    in1 = inA + (long)b * 524288;       // E_s bf16 [4096][128]
    W = Wb; sp = ssb;
  }

  int t = threadIdx.x, lane = t & 63, w = t >> 6;
  int l15 = lane & 15, l4 = lane >> 4;
  int wr = (w & 1) * 32, wc = (w >> 1) * 32;
  int ax = t >> 2, ac0 = (t & 3) * 8;
  int bco = t >> 2, bk = (t & 3) * 8;

  v4f acc[2][2] = {};

  auto loadA = [&](int it, v8bf& areg) {
    int dy = it >> 3, ks = it & 7;
    int ysrc = y + dy - 1;
    if ((unsigned)ysrc < 64u) {
      long n = (long)ysrc * 64 + ax;
      int cg = ks * 32 + ac0;
      const bf16* src;
      if (mode == 0)     src = in0 + n * 256 + cg;
      else if (cg < 128) src = in0 + n * 128 + cg;
      else               src = in1 + n * 128 + (cg - 128);
      areg = *(const v8bf*)src;
    } else {
#pragma unroll
      for (int i = 0; i < 8; ++i) areg[i] = (bf16)0.f;
    }
  };
  auto loadB = [&](int it, v8bf* breg) {
    int dy = it >> 3, ks = it & 7;
    const bf16* wk = W + (long)(co0 + bco) * 2304 + dy * 3 * 256 + ks * 32 + bk;
#pragma unroll
    for (int d = 0; d < 3; ++d) breg[d] = *(const v8bf*)(wk + d * 256);
  };

  // zero halo columns once (never overwritten: loop writes rows 1..64 only)
  if (t < 32) As[0][t] = (bf16)0.f;
  else if (t < 64) As[65][t - 32] = (bf16)0.f;

  v8bf areg, breg[3];
  loadA(0, areg);
  loadB(0, breg);

  for (int it = 0; it < 24; ++it) {
    __syncthreads();
    *(v8bf*)&As[ax + 1][ac0] = areg;
#pragma unroll
    for (int d = 0; d < 3; ++d) *(v8bf*)&Bs[d][bco][bk] = breg[d];
    __syncthreads();
    if (it < 23) { loadA(it + 1, areg); loadB(it + 1, breg); }
#pragma unroll
    for (int d = 0; d < 3; ++d) {
      v8bf af0 = *(const v8bf*)&As[wr + d + l15][l4 * 8];
      v8bf af1 = *(const v8bf*)&As[wr + 16 + d + l15][l4 * 8];
#pragma unroll
      for (int j = 0; j < 2; ++j) {
        v8bf bfr = *(const v8bf*)&Bs[d][wc + j * 16 + l15][l4 * 8];
        acc[0][j] = MFMA16(af0, bfr, acc[0][j]);
        acc[1][j] = MFMA16(af1, bfr, acc[1][j]);
      }
    }
  }
#pragma unroll
  for (int i = 0; i < 2; ++i) {
    int nb = y * 64 + wr + i * 16 + l4 * 4;
#pragma unroll
    for (int j = 0; j < 2; ++j) {
      int c = co0 + wc + j * 16 + l15;
      float scale = sp[c], shift = sp[128 + c];
      if (mode == 0) {
        bf16* o = (bf16*)out_ + ((long)(tsr * 2 + b) * 4096 + nb) * 128 + c;
#pragma unroll
        for (int r = 0; r < 4; ++r)
          o[r * 128] = (bf16)sf(fmaxf(acc[i][j][r] * scale + shift, 0.f));
      } else {
        v4f pk;
#pragma unroll
        for (int r = 0; r < 4; ++r)
          pk[r] = sf(fmaxf(acc[i][j][r] * scale + shift, 0.f));
        *(v4f*)((float*)out_ + ((long)b * 128 + c) * 4096 + nb) = pk;
      }
    }
  }
}

// ---------------- fused 1x1 convs; outputs stored in MFMA-fragment-major layouts ----------------
__global__ __launch_bounds__(256) void conv1_kernel(
    const bf16* __restrict__ feat_base,
    const float* __restrict__ cv_w, const float* __restrict__ k1_w, const float* __restrict__ q1_w,
    const float* __restrict__ k2_w, const float* __restrict__ q2_w,
    const float* __restrict__ cv_b, const float* __restrict__ k1_b, const float* __restrict__ q1_b,
    const float* __restrict__ k2_b, const float* __restrict__ q2_b,
    bf16* __restrict__ v_base, bf16* __restrict__ keyT, bf16* __restrict__ queryT,
    float* __restrict__ pmean)
{
  int nt = blockIdx.x;  // 0..127, 32 rows each
  int br = blockIdx.z >> 1, b = blockIdx.z & 1;
  long zid = br * 2 + b;
  const bf16* feat = feat_base + zid * 524288 + (long)nt * 4096;

  __shared__ bf16 As[32][40];
  __shared__ bf16 Bs[256][40];

  int t = threadIdx.x, lane = t & 63, w = t >> 6;
  int l15 = lane & 15, l4 = lane >> 4;
  int wr = (w & 1) * 16, wc = (w >> 1) * 128;

  const float* wrow;
  bool negk = false;
  if (t < 128)       wrow = cv_w + (long)t * 128;
  else if (t < 192) { wrow = (br ? k2_w : k1_w) + (long)(t - 128) * 128; negk = (br != 0); }
  else               wrow = (br ? q2_w : q1_w) + (long)(t - 192) * 128;

  v4f acc[8] = {};
  int ap = t >> 2, ak = (t & 3) * 8;

  for (int ks = 0; ks < 4; ++ks) {
    int ci0 = ks * 32;
    v8bf av;
    if (t < 128) av = *(const v8bf*)(feat + ap * 128 + ci0 + ak);
    float wv[32];
#pragma unroll
    for (int u = 0; u < 32; ++u) wv[u] = wrow[ci0 + u];
    if (negk) {
#pragma unroll
      for (int u = 0; u < 32; ++u) wv[u] = -wv[u];
    }
    __syncthreads();
    if (t < 128) *(v8bf*)&As[ap][ak] = av;
#pragma unroll
    for (int u = 0; u < 32; ++u) Bs[t][u] = (bf16)wv[u];
    __syncthreads();
    v8bf af = *(const v8bf*)&As[wr + l15][l4 * 8];
#pragma unroll
    for (int j = 0; j < 8; ++j) {
      v8bf bfr = *(const v8bf*)&Bs[wc + j * 16 + l15][l4 * 8];
      acc[j] = MFMA16(af, bfr, acc[j]);
    }
  }

  int nb = nt * 32 + wr + l4 * 4;
#pragma unroll
  for (int j = 0; j < 8; ++j) {
    int c = wc + j * 16 + l15;
    float bv;
    if (c < 128)      bv = cv_b[c];
    else if (c < 192) bv = br ? -k2_b[c - 128] : k1_b[c - 128];
    else              bv = (br ? q2_b : q1_b)[c - 192];
    float v0 = sf(acc[j][0] + bv), v1 = sf(acc[j][1] + bv);
    float v2 = sf(acc[j][2] + bv), v3 = sf(acc[j][3] + bv);
    if (c < 128) {
      long off = (long)(nb >> 5) * 4096 + (c >> 4) * 512 + ((nb >> 3) & 3) * 128 +
                 (c & 15) * 8 + (nb & 7);
      v4bf pk;
      pk[0] = (bf16)v0; pk[1] = (bf16)v1; pk[2] = (bf16)v2; pk[3] = (bf16)v3;
      *(v4bf*)(v_base + zid * 524288 + off) = pk;
      float s = v0 + v1 + v2 + v3;
      s += __shfl_xor(s, 16, 64);
      s += __shfl_xor(s, 32, 64);
      if (l4 == 0) atomicAdd(&pmean[zid * 128 + c], s);
    } else if (c < 192) {
      int cc = (c - 128) + br * 64;
      long off = (long)(nb >> 4) * 2048 + (cc >> 5) * 512 + ((cc >> 3) & 3) * 128 +
                 (nb & 15) * 8 + (cc & 7);
      bf16* kp = keyT + (long)b * 524288 + off;
      kp[0] = (bf16)v0; kp[8] = (bf16)v1; kp[16] = (bf16)v2; kp[24] = (bf16)v3;
    } else {
      int cc = (c - 192) + br * 64;
      long off = (long)(nb >> 4) * 2048 + (cc >> 5) * 512 + ((cc >> 3) & 3) * 128 +
                 (nb & 15) * 8 + (cc & 7);
      bf16* qp = queryT + (long)b * 524288 + off;
      qp[0] = (bf16)v0; qp[8] = (bf16)v1; qp[16] = (bf16)v2; qp[24] = (bf16)v3;
    }
  }
}

// ---------------- flash apply v11: 8 waves/block (16 waves/CU = 4/SIMD), per-wave private
// 32-m chunks of a 256-m super-iter, no in-loop barriers, same L2 traffic as v10 ----------
__global__ __launch_bounds__(512, 4) void apply_kernel(
    const bf16* __restrict__ keyT, const bf16* __restrict__ queryT,
    const bf16* __restrict__ v_base,
    const float* __restrict__ pmean,
    const float* __restrict__ g1_w, const float* __restrict__ g1_b,
    const float* __restrict__ g2_w, const float* __restrict__ g2_b,
    bf16* __restrict__ feat_base, float* __restrict__ d_out)
{
  int bid = blockIdx.x;
  int xcd = bid & 7;
  int z = xcd >> 1;                       // one (br,b) per XCD pair-slice
  int nt = (xcd & 1) * 64 + (bid >> 3);   // 0..127
  int br = z >> 1, b = z & 1;
  int n0 = nt * 32;
  const bf16* Xf = (br ? queryT : keyT) + (long)b * 524288 + (long)(n0 >> 4) * 2048;
  const bf16* Yf = (br ? keyT : queryT) + (long)b * 524288;
  const bf16* Vf = v_base + (long)(br * 2 + b) * 524288;
  bf16* feat = feat_base + (long)(br * 2 + b) * 524288 + (long)n0 * 128;

  // Psw (in-loop, per-wave private) and Fred (post-loop reduce) alias the same buffer.
  __shared__ __align__(16) char smem_raw[20480];   // max(8*32*40*2 = 20480, 128*36*4 = 18432)
  bf16 (*Psw)[32][40] = reinterpret_cast<bf16(*)[32][40]>(smem_raw);
  float (*Fred)[36] = reinterpret_cast<float(*)[36]>(smem_raw);
  __shared__ float rps[8][32];
  __shared__ float gl[128];
  __shared__ float hh[8];

  int t = threadIdx.x, lane = t & 63, w = t >> 6;   // w 0..7
  int l15 = lane & 15, l4 = lane >> 4;

  // inline channel-gate MLP (pmean ready before this kernel launches)
  {
    const float* pm = pmean + (br * 2 + b) * 128;
    if (t < 8) {
      float a = g1_b[t];
      for (int c = 0; c < 128; ++c) a += g1_w[t * 128 + c] * (pm[c] * (1.f / 4096.f));
      hh[t] = fmaxf(a, 0.f);
    }
    __syncthreads();
    if (t < 128) {
      float a = g2_b[t];
#pragma unroll
      for (int j = 0; j < 8; ++j) a += g2_w[t * 8 + j] * hh[j];
      gl[t] = sf(1.f / (1.f + __expf(-a)));
    }
  }

  // X A-fragments (full 32 rows, shared by all waves)
  v8bf af[2][4];
#pragma unroll
  for (int i = 0; i < 2; ++i)
#pragma unroll
    for (int k = 0; k < 4; ++k)
      af[i][k] = *(const v8bf*)(Xf + i * 2048 + k * 512 + lane * 8);

  v4f acc[2][8] = {};   // [n-frag][c-frag], partial over this wave's m
  float rp[2][4] = {};

  auto loadBy = [&](int mb, v8bf (&by)[2][4]) {
    const bf16* p = Yf + (long)(mb >> 4) * 2048 + lane * 8;
#pragma unroll
    for (int mf = 0; mf < 2; ++mf)
#pragma unroll
      for (int k = 0; k < 4; ++k) by[mf][k] = *(const v8bf*)(p + mf * 2048 + k * 512);
  };

  v8bf byA[2][4], byB[2][4];
  loadBy(w * 32, byA);

  auto subiter = [&](int it, v8bf (&byC)[2][4], v8bf (&byN)[2][4]) {
    int mb = it * 256 + w * 32;
    // V B-fragments for this m-chunk: issued early, consumed at PV (latency covered by QK+exp)
    v8bf vb[8];
    {
      const bf16* p = Vf + (long)(mb >> 5) * 4096 + lane * 8;
#pragma unroll
      for (int j = 0; j < 8; ++j) vb[j] = *(const v8bf*)(p + j * 512);
    }
    // QK: S[32n][32m] for this wave's m-chunk
    v4f sacc[2][2] = {};
#pragma unroll
    for (int k = 0; k < 4; ++k)
#pragma unroll
      for (int i = 0; i < 2; ++i)
#pragma unroll
        for (int mf = 0; mf < 2; ++mf)
          sacc[i][mf] = MFMA16(af[i][k], byC[mf][k], sacc[i][mf]);
    if (it < 15) loadBy(mb + 256, byN);   // prefetch next Y chunk
    // exp + row-sum partials + wave-private P^T staging (no barrier: same-wave DS in-order)
#pragma unroll
    for (int i = 0; i < 2; ++i)
#pragma unroll
      for (int mf = 0; mf < 2; ++mf)
#pragma unroll
        for (int r = 0; r < 4; ++r) {
          float e = __expf(fminf(fabsf(sacc[i][mf][r]), 80.f) - 50.f);
          rp[i][r] += e;
          Psw[w][i * 16 + l4 * 4 + r][mf * 16 + l15] = (bf16)e;
        }
    v8bf ap0 = *(const v8bf*)&Psw[w][l15][l4 * 8];
    v8bf ap1 = *(const v8bf*)&Psw[w][16 + l15][l4 * 8];
    // PV: k=32 over this wave's 32 m; 16 independent MFMAs
#pragma unroll
    for (int j = 0; j < 8; ++j) {
      acc[0][j] = MFMA16(ap0, vb[j], acc[0][j]);
      acc[1][j] = MFMA16(ap1, vb[j], acc[1][j]);
    }
  };

  for (int it2 = 0; it2 < 8; ++it2) {
    subiter(it2 * 2, byA, byB);
    subiter(it2 * 2 + 1, byB, byA);
  }

  // per-wave denominator partials (sum over this wave's m via l15 butterfly)
#pragma unroll
  for (int i = 0; i < 2; ++i)
#pragma unroll
    for (int r = 0; r < 4; ++r) {
      float v = rp[i][r];
      v += __shfl_xor(v, 1, 64);
      v += __shfl_xor(v, 2, 64);
      v += __shfl_xor(v, 4, 64);
      v += __shfl_xor(v, 8, 64);
      if (l15 == 0) rps[w][i * 16 + l4 * 4 + r] = v;
    }
  __syncthreads();   // all waves done with Psw reads + rps written

  // cross-wave numerator reduction into Fred[c][n] (aliases Psw; protected by barrier above)
#pragma unroll
  for (int ww = 0; ww < 8; ++ww) {
    if (w == ww) {
#pragma unroll
      for (int i = 0; i < 2; ++i)
#pragma unroll
        for (int j = 0; j < 8; ++j) {
          float* fp = &Fred[j * 16 + l15][i * 16 + l4 * 4];
          if (ww == 0) *(v4f*)fp = acc[i][j];
          else {
            v4f old = *(v4f*)fp;
#pragma unroll
            for (int r = 0; r < 4; ++r) old[r] += acc[i][j][r];
            *(v4f*)fp = old;
          }
        }
    }
    __syncthreads();
  }

  // epilogue: divide, gate, residual; fp32 E to d_out + bf16 E in-place over feat
  float* outE = d_out + (long)(br ? 1 : 2) * 1048576 + (long)b * 524288;
  int wr = (w & 1) * 16, wc = (w >> 1) * 32;
  int rowt = wr + l4 * 4;
  float dv[4];
#pragma unroll
  for (int r = 0; r < 4; ++r)
    dv[r] = fmaxf(rps[0][rowt + r] + rps[1][rowt + r] + rps[2][rowt + r] + rps[3][rowt + r] +
                  rps[4][rowt + r] + rps[5][rowt + r] + rps[6][rowt + r] + rps[7][rowt + r],
                  1e-30f);
#pragma unroll
  for (int j = 0; j < 2; ++j) {
    int c = wc + j * 16 + l15;
    float g = gl[c];
    v4f nm = *(const v4f*)&Fred[c][rowt];
    v4f pk;
#pragma unroll
    for (int r = 0; r < 4; ++r) {
      long fi = (long)(rowt + r) * 128 + c;
      float fv = (float)feat[fi];
      float val = sf(nm[r] / dv[r] * g + fv);
      pk[r] = val;
      feat[fi] = (bf16)val;   // in-place bf16 E for conv_cat (same thread read->write)
    }
    *(v4f*)(outE + (long)c * 4096 + n0 + rowt) = pk;
  }
}

// ---------------- launch ----------------
extern "C" void kernel_launch(void* const* d_in, const int* in_sizes, int n_in,
                              void* d_out, int out_size, void* d_ws, size_t ws_size,
                              hipStream_t stream)
{
  if (n_in != 33 || in_sizes[0] != 2097152 || in_sizes[2] != 294912 ||
      in_sizes[14] != 16384 || out_size != 3145728) {
    fill_kernel<<<12288, 256, 0, stream>>>((float*)d_out, 100.0f, 3145728);
    return;
  }
  if (ws_size < 12582912) {
    fill_kernel<<<12288, 256, 0, stream>>>((float*)d_out, 1.0f, 3145728);
    return;
  }

  const float* q_in = (const float*)d_in[0];
  const float* s_in = (const float*)d_in[1];
  char* ob = (char*)d_out;
  float* outf = (float*)d_out;

  float* pmean = (float*)(ob + 0);        // [4][128] f32 (atomic partial sums)
  bf16*  xin   = (bf16*)(ob + 4194304);   // [4][4096][256] bf16 NHWC

  char* ws = (char*)d_ws;
  bf16*  sfeat  = (bf16*)(ws + 0);         // [4][4096][128] bf16 (E bf16 in-place after apply)
  bf16*  vs     = (bf16*)(ws + 4194304);   // [4] frag-major V
  bf16*  keyT   = (bf16*)(ws + 8388608);   // [2] frag-major key
  bf16*  queryT = (bf16*)(ws + 10485760);  // [2] frag-major query
  bf16*  Wt01   = (bf16*)(ws + 8388608);   // alias: dead before conv1 writes keyT
  float* ss01   = (float*)(ws + 10485760); // alias: dead before conv1 writes queryT

  bool room = ws_size >= (size_t)13173760;
  bf16*  Wt2   = room ? (bf16*)(ws + 12582912) : (bf16*)(ws + 8388608);
  float* ss_cc = room ? (float*)(ws + 13172736) : (float*)(ws + 8978432);

  prep_all_kernel<<<room ? 3716 : 2563, 256, 0, stream>>>(
      s_in, q_in, xin,
      (const float*)d_in[2], (const float*)d_in[8],
      (const float*)d_in[3], (const float*)d_in[4], (const float*)d_in[5],
      (const float*)d_in[6], (const float*)d_in[7],
      (const float*)d_in[9], (const float*)d_in[10], (const float*)d_in[11],
      (const float*)d_in[12], (const float*)d_in[13],
      Wt01, ss01, pmean,
      (const float*)d_in[28], (const float*)d_in[29], (const float*)d_in[30],
      (const float*)d_in[31], (const float*)d_in[32],
      Wt2, ss_cc, room ? 1 : 0);

  convN_kernel<<<512, 256, 0, stream>>>(xin, Wt01, ss01, sfeat, 0);

  conv1_kernel<<<dim3(128, 1, 4), 256, 0, stream>>>(
      sfeat,
      (const float*)d_in[14], (const float*)d_in[16], (const float*)d_in[18],
      (const float*)d_in[20], (const float*)d_in[22],
      (const float*)d_in[15], (const float*)d_in[17], (const float*)d_in[19],
      (const float*)d_in[21], (const float*)d_in[23],
      vs, keyT, queryT, pmean);

  apply_kernel<<<512, 512, 0, stream>>>(
      keyT, queryT, vs, pmean,
      (const float*)d_in[24], (const float*)d_in[25],
      (const float*)d_in[26], (const float*)d_in[27],
      sfeat, outf);

  if (!room) {
    prep2_kernel<<<1153, 256, 0, stream>>>(
        (const float*)d_in[28], (const float*)d_in[29], (const float*)d_in[30],
        (const float*)d_in[31], (const float*)d_in[32], Wt2, ss_cc);
  }

  convN_kernel<<<256, 256, 0, stream>>>(sfeat, Wt2, ss_cc, outf, 1);
}

// Round 12
// 251.917 us; speedup vs baseline: 1.8524x; 1.8524x over previous
//
#include <hip/hip_runtime.h>

typedef __bf16 bf16;
typedef __bf16 v8bf __attribute__((ext_vector_type(8)));
typedef __bf16 v4bf __attribute__((ext_vector_type(4)));
typedef float v4f __attribute__((ext_vector_type(4)));

#define MFMA16(a, b, c) __builtin_amdgcn_mfma_f32_16x16x32_bf16(a, b, c, 0, 0, 0)

// NaN -> 0, clamp +-1e30. Insurance only.
__device__ __forceinline__ float sf(float x) {
  if (!(x == x)) return 0.f;
  return fminf(fmaxf(x, -1e30f), 1e30f);
}

// ---------------- guard fill (fp32 out) ----------------
__global__ __launch_bounds__(256) void fill_kernel(float* __restrict__ out, float v, int n) {
  int i = blockIdx.x * 256 + threadIdx.x;
  if (i < n) out[i] = v;
}

// ---------------- prep_all: tr (blocks 0..255) + stem weight prep + pmean zero
//                  + optional conv_cat prep (when ws has slack) ----------------
__global__ __launch_bounds__(256) void prep_all_kernel(
    const float* __restrict__ s_in, const float* __restrict__ q_in, bf16* __restrict__ xin,
    const float* __restrict__ ts_w, const float* __restrict__ tq_w,
    const float* ts_b, const float* ts_g, const float* ts_be, const float* ts_m, const float* ts_v,
    const float* tq_b, const float* tq_g, const float* tq_be, const float* tq_m, const float* tq_v,
    bf16* __restrict__ Wt01, float* __restrict__ ss01, float* __restrict__ pmean,
    const float* __restrict__ cc_w, const float* cc_g, const float* cc_be,
    const float* cc_m, const float* cc_v,
    bf16* __restrict__ Wt2, float* __restrict__ ss_cc, int do_prep2)
{
  int bx = blockIdx.x, t = threadIdx.x;
  if (bx < 256) {
    // NCHW fp32 -> NHWC bf16 transpose (coalesced reads along n)
    int nb = bx & 63, z = bx >> 6;
    const float* in = ((z >> 1) ? q_in : s_in) + (long)(z & 1) * 1048576;
    bf16* out = xin + (long)z * 1048576;
    int lane = t & 63, w = t >> 6;
    long n = (long)nb * 64 + lane;
#pragma unroll
    for (int i = 0; i < 8; ++i) {
      int c8 = w * 8 + i;
      v8bf o;
#pragma unroll
      for (int j = 0; j < 8; ++j) o[j] = (bf16)in[(long)(c8 * 8 + j) * 4096 + n];
      *(v8bf*)(out + n * 256 + c8 * 8) = o;
    }
    return;
  }
  int idx = (bx - 256) * 256 + t;
  if (idx < 589824) {
    int which = idx / 294912;
    int rem = idx - which * 294912;
    int co = rem / 2304;
    int r2 = rem - co * 2304;
    int tap = r2 >> 8;
    int ci = r2 & 255;
    const float* W = which ? tq_w : ts_w;
    Wt01[idx] = (bf16)W[(co * 256 + ci) * 9 + tap];
  } else if (idx < 590080) {
    int i = idx - 589824;
    int which = i >> 7, c = i & 127;
    float g, be, m, vv, bias;
    if (which == 0) { g=ts_g[c]; be=ts_be[c]; m=ts_m[c]; vv=ts_v[c]; bias=ts_b[c]; }
    else            { g=tq_g[c]; be=tq_be[c]; m=tq_m[c]; vv=tq_v[c]; bias=tq_b[c]; }
    float scale = g / sqrtf(vv + 1e-5f);
    ss01[which * 256 + c] = sf(scale);
    ss01[which * 256 + 128 + c] = sf((bias - m) * scale + be);
  } else if (idx < 590592) {
    pmean[idx - 590080] = 0.f;
  } else if (do_prep2) {
    int idx2 = idx - 590592;
    if (idx2 < 294912) {
      int co = idx2 / 2304;
      int r2 = idx2 - co * 2304;
      int tap = r2 >> 8;
      int ci = r2 & 255;
      Wt2[idx2] = (bf16)cc_w[(co * 256 + ci) * 9 + tap];
    } else if (idx2 < 295040) {
      int c = idx2 - 294912;
      float scale = cc_g[c] / sqrtf(cc_v[c] + 1e-5f);
      ss_cc[c] = sf(scale);
      ss_cc[128 + c] = sf(-cc_m[c] * scale + cc_be[c]);
    }
  }
}

// ---------------- prep2 fallback (after apply; over dead keyT) ----------------
__global__ __launch_bounds__(256) void prep2_kernel(
    const float* __restrict__ cc_w, const float* cc_g, const float* cc_be,
    const float* cc_m, const float* cc_v,
    bf16* __restrict__ Wt2, float* __restrict__ ss_cc)
{
  int idx = blockIdx.x * 256 + threadIdx.x;
  if (idx < 294912) {
    int co = idx / 2304;
    int r2 = idx - co * 2304;
    int tap = r2 >> 8;
    int ci = r2 & 255;
    Wt2[idx] = (bf16)cc_w[(co * 256 + ci) * 9 + tap];
  } else if (idx < 295040) {
    int c = idx - 294912;
    float scale = cc_g[c] / sqrtf(cc_v[c] + 1e-5f);
    ss_cc[c] = sf(scale);
    ss_cc[128 + c] = sf(-cc_m[c] * scale + cc_be[c]);
  }
}

// ---------------- 3x3 conv implicit GEMM over NHWC bf16 input, coalesced A staging;
// XCD-swizzled flat grid ----------
__global__ __launch_bounds__(256) void convN_kernel(
    const bf16* __restrict__ inA,
    const bf16* __restrict__ Wb, const float* __restrict__ ssb,
    void* __restrict__ out_, int mode)
{
  __shared__ bf16 As[66][40];
  __shared__ bf16 Bs[3][64][40];

  int bid = blockIdx.x;
  int xcd = bid & 7, slot = bid >> 3;
  int y, co0, tsr, b;
  if (mode == 0) {
    int z = xcd >> 1;
    tsr = z >> 1; b = z & 1;
    co0 = (xcd & 1) * 64;
    y = slot;
  } else {
    int combo = xcd >> 1;
    co0 = (combo >> 1) * 64;
    b = combo & 1;
    tsr = 0;
    y = (xcd & 1) * 32 + slot;
  }

  const bf16 *in0, *in1;
  const bf16* W;
  const float* sp;
  if (mode == 0) {
    in0 = inA + (long)(tsr * 2 + b) * 1048576;  // [4096][256]
    in1 = nullptr;
    W = Wb + (long)tsr * 294912;
    sp = ssb + tsr * 256;
  } else {
    in0 = inA + (long)(2 + b) * 524288; // E_q bf16 [4096][128]
    in1 = inA + (long)b * 524288;       // E_s bf16 [4096][128]
    W = Wb; sp = ssb;
  }

  int t = threadIdx.x, lane = t & 63, w = t >> 6;
  int l15 = lane & 15, l4 = lane >> 4;
  int wr = (w & 1) * 32, wc = (w >> 1) * 32;
  int ax = t >> 2, ac0 = (t & 3) * 8;
  int bco = t >> 2, bk = (t & 3) * 8;

  v4f acc[2][2] = {};

  auto loadA = [&](int it, v8bf& areg) {
    int dy = it >> 3, ks = it & 7;
    int ysrc = y + dy - 1;
    if ((unsigned)ysrc < 64u) {
      long n = (long)ysrc * 64 + ax;
      int cg = ks * 32 + ac0;
      const bf16* src;
      if (mode == 0)     src = in0 + n * 256 + cg;
      else if (cg < 128) src = in0 + n * 128 + cg;
      else               src = in1 + n * 128 + (cg - 128);
      areg = *(const v8bf*)src;
    } else {
#pragma unroll
      for (int i = 0; i < 8; ++i) areg[i] = (bf16)0.f;
    }
  };
  auto loadB = [&](int it, v8bf* breg) {
    int dy = it >> 3, ks = it & 7;
    const bf16* wk = W + (long)(co0 + bco) * 2304 + dy * 3 * 256 + ks * 32 + bk;
#pragma unroll
    for (int d = 0; d < 3; ++d) breg[d] = *(const v8bf*)(wk + d * 256);
  };

  // zero halo columns once (never overwritten: loop writes rows 1..64 only)
  if (t < 32) As[0][t] = (bf16)0.f;
  else if (t < 64) As[65][t - 32] = (bf16)0.f;

  v8bf areg, breg[3];
  loadA(0, areg);
  loadB(0, breg);

  for (int it = 0; it < 24; ++it) {
    __syncthreads();
    *(v8bf*)&As[ax + 1][ac0] = areg;
#pragma unroll
    for (int d = 0; d < 3; ++d) *(v8bf*)&Bs[d][bco][bk] = breg[d];
    __syncthreads();
    if (it < 23) { loadA(it + 1, areg); loadB(it + 1, breg); }
#pragma unroll
    for (int d = 0; d < 3; ++d) {
      v8bf af0 = *(const v8bf*)&As[wr + d + l15][l4 * 8];
      v8bf af1 = *(const v8bf*)&As[wr + 16 + d + l15][l4 * 8];
#pragma unroll
      for (int j = 0; j < 2; ++j) {
        v8bf bfr = *(const v8bf*)&Bs[d][wc + j * 16 + l15][l4 * 8];
        acc[0][j] = MFMA16(af0, bfr, acc[0][j]);
        acc[1][j] = MFMA16(af1, bfr, acc[1][j]);
      }
    }
  }
#pragma unroll
  for (int i = 0; i < 2; ++i) {
    int nb = y * 64 + wr + i * 16 + l4 * 4;
#pragma unroll
    for (int j = 0; j < 2; ++j) {
      int c = co0 + wc + j * 16 + l15;
      float scale = sp[c], shift = sp[128 + c];
      if (mode == 0) {
        bf16* o = (bf16*)out_ + ((long)(tsr * 2 + b) * 4096 + nb) * 128 + c;
#pragma unroll
        for (int r = 0; r < 4; ++r)
          o[r * 128] = (bf16)sf(fmaxf(acc[i][j][r] * scale + shift, 0.f));
      } else {
        v4f pk;
#pragma unroll
        for (int r = 0; r < 4; ++r)
          pk[r] = sf(fmaxf(acc[i][j][r] * scale + shift, 0.f));
        *(v4f*)((float*)out_ + ((long)b * 128 + c) * 4096 + nb) = pk;
      }
    }
  }
}

// ---------------- fused 1x1 convs; outputs stored in MFMA-fragment-major layouts ----------------
__global__ __launch_bounds__(256) void conv1_kernel(
    const bf16* __restrict__ feat_base,
    const float* __restrict__ cv_w, const float* __restrict__ k1_w, const float* __restrict__ q1_w,
    const float* __restrict__ k2_w, const float* __restrict__ q2_w,
    const float* __restrict__ cv_b, const float* __restrict__ k1_b, const float* __restrict__ q1_b,
    const float* __restrict__ k2_b, const float* __restrict__ q2_b,
    bf16* __restrict__ v_base, bf16* __restrict__ keyT, bf16* __restrict__ queryT,
    float* __restrict__ pmean)
{
  int nt = blockIdx.x;  // 0..127, 32 rows each
  int br = blockIdx.z >> 1, b = blockIdx.z & 1;
  long zid = br * 2 + b;
  const bf16* feat = feat_base + zid * 524288 + (long)nt * 4096;

  __shared__ bf16 As[32][40];
  __shared__ bf16 Bs[256][40];

  int t = threadIdx.x, lane = t & 63, w = t >> 6;
  int l15 = lane & 15, l4 = lane >> 4;
  int wr = (w & 1) * 16, wc = (w >> 1) * 128;

  const float* wrow;
  bool negk = false;
  if (t < 128)       wrow = cv_w + (long)t * 128;
  else if (t < 192) { wrow = (br ? k2_w : k1_w) + (long)(t - 128) * 128; negk = (br != 0); }
  else               wrow = (br ? q2_w : q1_w) + (long)(t - 192) * 128;

  v4f acc[8] = {};
  int ap = t >> 2, ak = (t & 3) * 8;

  for (int ks = 0; ks < 4; ++ks) {
    int ci0 = ks * 32;
    v8bf av;
    if (t < 128) av = *(const v8bf*)(feat + ap * 128 + ci0 + ak);
    float wv[32];
#pragma unroll
    for (int u = 0; u < 32; ++u) wv[u] = wrow[ci0 + u];
    if (negk) {
#pragma unroll
      for (int u = 0; u < 32; ++u) wv[u] = -wv[u];
    }
    __syncthreads();
    if (t < 128) *(v8bf*)&As[ap][ak] = av;
#pragma unroll
    for (int u = 0; u < 32; ++u) Bs[t][u] = (bf16)wv[u];
    __syncthreads();
    v8bf af = *(const v8bf*)&As[wr + l15][l4 * 8];
#pragma unroll
    for (int j = 0; j < 8; ++j) {
      v8bf bfr = *(const v8bf*)&Bs[wc + j * 16 + l15][l4 * 8];
      acc[j] = MFMA16(af, bfr, acc[j]);
    }
  }

  int nb = nt * 32 + wr + l4 * 4;
#pragma unroll
  for (int j = 0; j < 8; ++j) {
    int c = wc + j * 16 + l15;
    float bv;
    if (c < 128)      bv = cv_b[c];
    else if (c < 192) bv = br ? -k2_b[c - 128] : k1_b[c - 128];
    else              bv = (br ? q2_b : q1_b)[c - 192];
    float v0 = sf(acc[j][0] + bv), v1 = sf(acc[j][1] + bv);
    float v2 = sf(acc[j][2] + bv), v3 = sf(acc[j][3] + bv);
    if (c < 128) {
      long off = (long)(nb >> 5) * 4096 + (c >> 4) * 512 + ((nb >> 3) & 3) * 128 +
                 (c & 15) * 8 + (nb & 7);
      v4bf pk;
      pk[0] = (bf16)v0; pk[1] = (bf16)v1; pk[2] = (bf16)v2; pk[3] = (bf16)v3;
      *(v4bf*)(v_base + zid * 524288 + off) = pk;
      float s = v0 + v1 + v2 + v3;
      s += __shfl_xor(s, 16, 64);
      s += __shfl_xor(s, 32, 64);
      if (l4 == 0) atomicAdd(&pmean[zid * 128 + c], s);
    } else if (c < 192) {
      int cc = (c - 128) + br * 64;
      long off = (long)(nb >> 4) * 2048 + (cc >> 5) * 512 + ((cc >> 3) & 3) * 128 +
                 (nb & 15) * 8 + (cc & 7);
      bf16* kp = keyT + (long)b * 524288 + off;
      kp[0] = (bf16)v0; kp[8] = (bf16)v1; kp[16] = (bf16)v2; kp[24] = (bf16)v3;
    } else {
      int cc = (c - 192) + br * 64;
      long off = (long)(nb >> 4) * 2048 + (cc >> 5) * 512 + ((cc >> 3) & 3) * 128 +
                 (nb & 15) * 8 + (cc & 7);
      bf16* qp = queryT + (long)b * 524288 + off;
      qp[0] = (bf16)v0; qp[8] = (bf16)v1; qp[16] = (bf16)v2; qp[24] = (bf16)v3;
    }
  }
}

// ---------------- flash apply v11b: 8 waves/block, per-wave private 32-m chunks, no in-loop
// barriers; __launch_bounds__(512,2) -> 256-VGPR cap (r11's (512,4) forced spill) ----------
__global__ __launch_bounds__(512, 2) void apply_kernel(
    const bf16* __restrict__ keyT, const bf16* __restrict__ queryT,
    const bf16* __restrict__ v_base,
    const float* __restrict__ pmean,
    const float* __restrict__ g1_w, const float* __restrict__ g1_b,
    const float* __restrict__ g2_w, const float* __restrict__ g2_b,
    bf16* __restrict__ feat_base, float* __restrict__ d_out)
{
  int bid = blockIdx.x;
  int xcd = bid & 7;
  int z = xcd >> 1;                       // one (br,b) per XCD pair-slice
  int nt = (xcd & 1) * 64 + (bid >> 3);   // 0..127
  int br = z >> 1, b = z & 1;
  int n0 = nt * 32;
  const bf16* Xf = (br ? queryT : keyT) + (long)b * 524288 + (long)(n0 >> 4) * 2048;
  const bf16* Yf = (br ? keyT : queryT) + (long)b * 524288;
  const bf16* Vf = v_base + (long)(br * 2 + b) * 524288;
  bf16* feat = feat_base + (long)(br * 2 + b) * 524288 + (long)n0 * 128;

  // Psw (in-loop, per-wave private) and Fred (post-loop reduce) alias the same buffer.
  __shared__ __align__(16) char smem_raw[20480];   // max(8*32*40*2 = 20480, 128*36*4 = 18432)
  bf16 (*Psw)[32][40] = reinterpret_cast<bf16(*)[32][40]>(smem_raw);
  float (*Fred)[36] = reinterpret_cast<float(*)[36]>(smem_raw);
  __shared__ float rps[8][32];
  __shared__ float gl[128];
  __shared__ float hh[8];

  int t = threadIdx.x, lane = t & 63, w = t >> 6;   // w 0..7
  int l15 = lane & 15, l4 = lane >> 4;

  // inline channel-gate MLP (pmean ready before this kernel launches)
  {
    const float* pm = pmean + (br * 2 + b) * 128;
    if (t < 8) {
      float a = g1_b[t];
      for (int c = 0; c < 128; ++c) a += g1_w[t * 128 + c] * (pm[c] * (1.f / 4096.f));
      hh[t] = fmaxf(a, 0.f);
    }
    __syncthreads();
    if (t < 128) {
      float a = g2_b[t];
#pragma unroll
      for (int j = 0; j < 8; ++j) a += g2_w[t * 8 + j] * hh[j];
      gl[t] = sf(1.f / (1.f + __expf(-a)));
    }
  }

  // X A-fragments (full 32 rows, shared by all waves)
  v8bf af[2][4];
#pragma unroll
  for (int i = 0; i < 2; ++i)
#pragma unroll
    for (int k = 0; k < 4; ++k)
      af[i][k] = *(const v8bf*)(Xf + i * 2048 + k * 512 + lane * 8);

  v4f acc[2][8] = {};   // [n-frag][c-frag], partial over this wave's m
  float rp[2][4] = {};

  auto loadBy = [&](int mb, v8bf (&by)[2][4]) {
    const bf16* p = Yf + (long)(mb >> 4) * 2048 + lane * 8;
#pragma unroll
    for (int mf = 0; mf < 2; ++mf)
#pragma unroll
      for (int k = 0; k < 4; ++k) by[mf][k] = *(const v8bf*)(p + mf * 2048 + k * 512);
  };

  v8bf byA[2][4], byB[2][4];
  loadBy(w * 32, byA);

  auto subiter = [&](int it, v8bf (&byC)[2][4], v8bf (&byN)[2][4]) {
    int mb = it * 256 + w * 32;
    // V B-fragments for this m-chunk: issued early, consumed at PV (latency covered by QK+exp)
    v8bf vb[8];
    {
      const bf16* p = Vf + (long)(mb >> 5) * 4096 + lane * 8;
#pragma unroll
      for (int j = 0; j < 8; ++j) vb[j] = *(const v8bf*)(p + j * 512);
    }
    // QK: S[32n][32m] for this wave's m-chunk
    v4f sacc[2][2] = {};
#pragma unroll
    for (int k = 0; k < 4; ++k)
#pragma unroll
      for (int i = 0; i < 2; ++i)
#pragma unroll
        for (int mf = 0; mf < 2; ++mf)
          sacc[i][mf] = MFMA16(af[i][k], byC[mf][k], sacc[i][mf]);
    if (it < 15) loadBy(mb + 256, byN);   // prefetch next Y chunk
    // exp + row-sum partials + wave-private P^T staging (no barrier: same-wave DS in-order)
#pragma unroll
    for (int i = 0; i < 2; ++i)
#pragma unroll
      for (int mf = 0; mf < 2; ++mf)
#pragma unroll
        for (int r = 0; r < 4; ++r) {
          float e = __expf(fminf(fabsf(sacc[i][mf][r]), 80.f) - 50.f);
          rp[i][r] += e;
          Psw[w][i * 16 + l4 * 4 + r][mf * 16 + l15] = (bf16)e;
        }
    v8bf ap0 = *(const v8bf*)&Psw[w][l15][l4 * 8];
    v8bf ap1 = *(const v8bf*)&Psw[w][16 + l15][l4 * 8];
    // PV: k=32 over this wave's 32 m; 16 independent MFMAs
#pragma unroll
    for (int j = 0; j < 8; ++j) {
      acc[0][j] = MFMA16(ap0, vb[j], acc[0][j]);
      acc[1][j] = MFMA16(ap1, vb[j], acc[1][j]);
    }
  };

  for (int it2 = 0; it2 < 8; ++it2) {
    subiter(it2 * 2, byA, byB);
    subiter(it2 * 2 + 1, byB, byA);
  }

  // per-wave denominator partials (sum over this wave's m via l15 butterfly)
#pragma unroll
  for (int i = 0; i < 2; ++i)
#pragma unroll
    for (int r = 0; r < 4; ++r) {
      float v = rp[i][r];
      v += __shfl_xor(v, 1, 64);
      v += __shfl_xor(v, 2, 64);
      v += __shfl_xor(v, 4, 64);
      v += __shfl_xor(v, 8, 64);
      if (l15 == 0) rps[w][i * 16 + l4 * 4 + r] = v;
    }
  __syncthreads();   // all waves done with Psw reads + rps written

  // cross-wave numerator reduction into Fred[c][n] (aliases Psw; protected by barrier above)
#pragma unroll
  for (int ww = 0; ww < 8; ++ww) {
    if (w == ww) {
#pragma unroll
      for (int i = 0; i < 2; ++i)
#pragma unroll
        for (int j = 0; j < 8; ++j) {
          float* fp = &Fred[j * 16 + l15][i * 16 + l4 * 4];
          if (ww == 0) *(v4f*)fp = acc[i][j];
          else {
            v4f old = *(v4f*)fp;
#pragma unroll
            for (int r = 0; r < 4; ++r) old[r] += acc[i][j][r];
            *(v4f*)fp = old;
          }
        }
    }
    __syncthreads();
  }

  // epilogue: divide, gate, residual; fp32 E to d_out + bf16 E in-place over feat
  float* outE = d_out + (long)(br ? 1 : 2) * 1048576 + (long)b * 524288;
  int wr = (w & 1) * 16, wc = (w >> 1) * 32;
  int rowt = wr + l4 * 4;
  float dv[4];
#pragma unroll
  for (int r = 0; r < 4; ++r)
    dv[r] = fmaxf(rps[0][rowt + r] + rps[1][rowt + r] + rps[2][rowt + r] + rps[3][rowt + r] +
                  rps[4][rowt + r] + rps[5][rowt + r] + rps[6][rowt + r] + rps[7][rowt + r],
                  1e-30f);
#pragma unroll
  for (int j = 0; j < 2; ++j) {
    int c = wc + j * 16 + l15;
    float g = gl[c];
    v4f nm = *(const v4f*)&Fred[c][rowt];
    v4f pk;
#pragma unroll
    for (int r = 0; r < 4; ++r) {
      long fi = (long)(rowt + r) * 128 + c;
      float fv = (float)feat[fi];
      float val = sf(nm[r] / dv[r] * g + fv);
      pk[r] = val;
      feat[fi] = (bf16)val;   // in-place bf16 E for conv_cat (same thread read->write)
    }
    *(v4f*)(outE + (long)c * 4096 + n0 + rowt) = pk;
  }
}

// ---------------- launch ----------------
extern "C" void kernel_launch(void* const* d_in, const int* in_sizes, int n_in,
                              void* d_out, int out_size, void* d_ws, size_t ws_size,
                              hipStream_t stream)
{
  if (n_in != 33 || in_sizes[0] != 2097152 || in_sizes[2] != 294912 ||
      in_sizes[14] != 16384 || out_size != 3145728) {
    fill_kernel<<<12288, 256, 0, stream>>>((float*)d_out, 100.0f, 3145728);
    return;
  }
  if (ws_size < 12582912) {
    fill_kernel<<<12288, 256, 0, stream>>>((float*)d_out, 1.0f, 3145728);
    return;
  }

  const float* q_in = (const float*)d_in[0];
  const float* s_in = (const float*)d_in[1];
  char* ob = (char*)d_out;
  float* outf = (float*)d_out;

  float* pmean = (float*)(ob + 0);        // [4][128] f32 (atomic partial sums)
  bf16*  xin   = (bf16*)(ob + 4194304);   // [4][4096][256] bf16 NHWC

  char* ws = (char*)d_ws;
  bf16*  sfeat  = (bf16*)(ws + 0);         // [4][4096][128] bf16 (E bf16 in-place after apply)
  bf16*  vs     = (bf16*)(ws + 4194304);   // [4] frag-major V
  bf16*  keyT   = (bf16*)(ws + 8388608);   // [2] frag-major key
  bf16*  queryT = (bf16*)(ws + 10485760);  // [2] frag-major query
  bf16*  Wt01   = (bf16*)(ws + 8388608);   // alias: dead before conv1 writes keyT
  float* ss01   = (float*)(ws + 10485760); // alias: dead before conv1 writes queryT

  bool room = ws_size >= (size_t)13173760;
  bf16*  Wt2   = room ? (bf16*)(ws + 12582912) : (bf16*)(ws + 8388608);
  float* ss_cc = room ? (float*)(ws + 13172736) : (float*)(ws + 8978432);

  prep_all_kernel<<<room ? 3716 : 2563, 256, 0, stream>>>(
      s_in, q_in, xin,
      (const float*)d_in[2], (const float*)d_in[8],
      (const float*)d_in[3], (const float*)d_in[4], (const float*)d_in[5],
      (const float*)d_in[6], (const float*)d_in[7],
      (const float*)d_in[9], (const float*)d_in[10], (const float*)d_in[11],
      (const float*)d_in[12], (const float*)d_in[13],
      Wt01, ss01, pmean,
      (const float*)d_in[28], (const float*)d_in[29], (const float*)d_in[30],
      (const float*)d_in[31], (const float*)d_in[32],
      Wt2, ss_cc, room ? 1 : 0);

  convN_kernel<<<512, 256, 0, stream>>>(xin, Wt01, ss01, sfeat, 0);

  conv1_kernel<<<dim3(128, 1, 4), 256, 0, stream>>>(
      sfeat,
      (const float*)d_in[14], (const float*)d_in[16], (const float*)d_in[18],
      (const float*)d_in[20], (const float*)d_in[22],
      (const float*)d_in[15], (const float*)d_in[17], (const float*)d_in[19],
      (const float*)d_in[21], (const float*)d_in[23],
      vs, keyT, queryT, pmean);

  apply_kernel<<<512, 512, 0, stream>>>(
      keyT, queryT, vs, pmean,
      (const float*)d_in[24], (const float*)d_in[25],
      (const float*)d_in[26], (const float*)d_in[27],
      sfeat, outf);

  if (!room) {
    prep2_kernel<<<1153, 256, 0, stream>>>(
        (const float*)d_in[28], (const float*)d_in[29], (const float*)d_in[30],
        (const float*)d_in[31], (const float*)d_in[32], Wt2, ss_cc);
  }

  convN_kernel<<<256, 256, 0, stream>>>(sfeat, Wt2, ss_cc, outf, 1);
}

// Round 13
// 248.918 us; speedup vs baseline: 1.8747x; 1.0120x over previous
//
#include <hip/hip_runtime.h>

typedef __bf16 bf16;
typedef __bf16 v8bf __attribute__((ext_vector_type(8)));
typedef __bf16 v4bf __attribute__((ext_vector_type(4)));
typedef float v4f __attribute__((ext_vector_type(4)));

#define MFMA16(a, b, c) __builtin_amdgcn_mfma_f32_16x16x32_bf16(a, b, c, 0, 0, 0)

// NaN -> 0, clamp +-1e30. Insurance only.
__device__ __forceinline__ float sf(float x) {
  if (!(x == x)) return 0.f;
  return fminf(fmaxf(x, -1e30f), 1e30f);
}

// ---------------- guard fill (fp32 out) ----------------
__global__ __launch_bounds__(256) void fill_kernel(float* __restrict__ out, float v, int n) {
  int i = blockIdx.x * 256 + threadIdx.x;
  if (i < n) out[i] = v;
}

// ---------------- prep_all: tr (blocks 0..255) + stem weight prep + pmean zero
//                  + optional conv_cat prep (when ws has slack) ----------------
__global__ __launch_bounds__(256) void prep_all_kernel(
    const float* __restrict__ s_in, const float* __restrict__ q_in, bf16* __restrict__ xin,
    const float* __restrict__ ts_w, const float* __restrict__ tq_w,
    const float* ts_b, const float* ts_g, const float* ts_be, const float* ts_m, const float* ts_v,
    const float* tq_b, const float* tq_g, const float* tq_be, const float* tq_m, const float* tq_v,
    bf16* __restrict__ Wt01, float* __restrict__ ss01, float* __restrict__ pmean,
    const float* __restrict__ cc_w, const float* cc_g, const float* cc_be,
    const float* cc_m, const float* cc_v,
    bf16* __restrict__ Wt2, float* __restrict__ ss_cc, int do_prep2)
{
  int bx = blockIdx.x, t = threadIdx.x;
  if (bx < 256) {
    // NCHW fp32 -> NHWC bf16 transpose (coalesced reads along n)
    int nb = bx & 63, z = bx >> 6;
    const float* in = ((z >> 1) ? q_in : s_in) + (long)(z & 1) * 1048576;
    bf16* out = xin + (long)z * 1048576;
    int lane = t & 63, w = t >> 6;
    long n = (long)nb * 64 + lane;
#pragma unroll
    for (int i = 0; i < 8; ++i) {
      int c8 = w * 8 + i;
      v8bf o;
#pragma unroll
      for (int j = 0; j < 8; ++j) o[j] = (bf16)in[(long)(c8 * 8 + j) * 4096 + n];
      *(v8bf*)(out + n * 256 + c8 * 8) = o;
    }
    return;
  }
  int idx = (bx - 256) * 256 + t;
  if (idx < 589824) {
    int which = idx / 294912;
    int rem = idx - which * 294912;
    int co = rem / 2304;
    int r2 = rem - co * 2304;
    int tap = r2 >> 8;
    int ci = r2 & 255;
    const float* W = which ? tq_w : ts_w;
    Wt01[idx] = (bf16)W[(co * 256 + ci) * 9 + tap];
  } else if (idx < 590080) {
    int i = idx - 589824;
    int which = i >> 7, c = i & 127;
    float g, be, m, vv, bias;
    if (which == 0) { g=ts_g[c]; be=ts_be[c]; m=ts_m[c]; vv=ts_v[c]; bias=ts_b[c]; }
    else            { g=tq_g[c]; be=tq_be[c]; m=tq_m[c]; vv=tq_v[c]; bias=tq_b[c]; }
    float scale = g / sqrtf(vv + 1e-5f);
    ss01[which * 256 + c] = sf(scale);
    ss01[which * 256 + 128 + c] = sf((bias - m) * scale + be);
  } else if (idx < 590592) {
    pmean[idx - 590080] = 0.f;
  } else if (do_prep2) {
    int idx2 = idx - 590592;
    if (idx2 < 294912) {
      int co = idx2 / 2304;
      int r2 = idx2 - co * 2304;
      int tap = r2 >> 8;
      int ci = r2 & 255;
      Wt2[idx2] = (bf16)cc_w[(co * 256 + ci) * 9 + tap];
    } else if (idx2 < 295040) {
      int c = idx2 - 294912;
      float scale = cc_g[c] / sqrtf(cc_v[c] + 1e-5f);
      ss_cc[c] = sf(scale);
      ss_cc[128 + c] = sf(-cc_m[c] * scale + cc_be[c]);
    }
  }
}

// ---------------- prep2 fallback (after apply; over dead keyT) ----------------
__global__ __launch_bounds__(256) void prep2_kernel(
    const float* __restrict__ cc_w, const float* cc_g, const float* cc_be,
    const float* cc_m, const float* cc_v,
    bf16* __restrict__ Wt2, float* __restrict__ ss_cc)
{
  int idx = blockIdx.x * 256 + threadIdx.x;
  if (idx < 294912) {
    int co = idx / 2304;
    int r2 = idx - co * 2304;
    int tap = r2 >> 8;
    int ci = r2 & 255;
    Wt2[idx] = (bf16)cc_w[(co * 256 + ci) * 9 + tap];
  } else if (idx < 295040) {
    int c = idx - 294912;
    float scale = cc_g[c] / sqrtf(cc_v[c] + 1e-5f);
    ss_cc[c] = sf(scale);
    ss_cc[128 + c] = sf(-cc_m[c] * scale + cc_be[c]);
  }
}

// ---------------- 3x3 conv implicit GEMM, 64-ci K-step (12 iters, half the barriers);
// XCD-swizzled flat grid ----------
__global__ __launch_bounds__(256) void convN_kernel(
    const bf16* __restrict__ inA,
    const bf16* __restrict__ Wb, const float* __restrict__ ssb,
    void* __restrict__ out_, int mode)
{
  __shared__ bf16 As[66][88];      // stride 88 bf16 = 44 dw; gcd(44,32)=4 -> 2-way max
  __shared__ bf16 Bs[3][64][88];

  int bid = blockIdx.x;
  int xcd = bid & 7, slot = bid >> 3;
  int y, co0, tsr, b;
  if (mode == 0) {
    int z = xcd >> 1;
    tsr = z >> 1; b = z & 1;
    co0 = (xcd & 1) * 64;
    y = slot;
  } else {
    int combo = xcd >> 1;
    co0 = (combo >> 1) * 64;
    b = combo & 1;
    tsr = 0;
    y = (xcd & 1) * 32 + slot;
  }

  const bf16 *in0, *in1;
  const bf16* W;
  const float* sp;
  if (mode == 0) {
    in0 = inA + (long)(tsr * 2 + b) * 1048576;  // [4096][256]
    in1 = nullptr;
    W = Wb + (long)tsr * 294912;
    sp = ssb + tsr * 256;
  } else {
    in0 = inA + (long)(2 + b) * 524288; // E_q bf16 [4096][128]
    in1 = inA + (long)b * 524288;       // E_s bf16 [4096][128]
    W = Wb; sp = ssb;
  }

  int t = threadIdx.x, lane = t & 63, w = t >> 6;
  int l15 = lane & 15, l4 = lane >> 4;
  int wr = (w & 1) * 32, wc = (w >> 1) * 32;
  int ax = t >> 2, ac0 = (t & 3) * 8;
  int bco = t >> 2, bk = (t & 3) * 8;

  v4f acc[2][2] = {};

  // it = dy*4 + ks2; 12 iters; 64 ci per iter
  auto loadA = [&](int it, v8bf* areg) {
    int dy = it >> 2, ks2 = it & 3;
    int ysrc = y + dy - 1;
    if ((unsigned)ysrc < 64u) {
      long n = (long)ysrc * 64 + ax;
      int c0 = ks2 * 64 + ac0, c1 = c0 + 32;
      if (mode == 0) {
        const bf16* src = in0 + n * 256 + c0;
        areg[0] = *(const v8bf*)src;
        areg[1] = *(const v8bf*)(src + 32);
      } else {
        areg[0] = *(const v8bf*)(c0 < 128 ? in0 + n * 128 + c0 : in1 + n * 128 + (c0 - 128));
        areg[1] = *(const v8bf*)(c1 < 128 ? in0 + n * 128 + c1 : in1 + n * 128 + (c1 - 128));
      }
    } else {
#pragma unroll
      for (int i = 0; i < 8; ++i) { areg[0][i] = (bf16)0.f; areg[1][i] = (bf16)0.f; }
    }
  };
  auto loadB = [&](int it, v8bf (*breg)[2]) {
    int dy = it >> 2, ks2 = it & 3;
    const bf16* wk = W + (long)(co0 + bco) * 2304 + dy * 3 * 256 + ks2 * 64 + bk;
#pragma unroll
    for (int d = 0; d < 3; ++d) {
      breg[d][0] = *(const v8bf*)(wk + d * 256);
      breg[d][1] = *(const v8bf*)(wk + d * 256 + 32);
    }
  };

  // zero halo columns once (cols 0..63; never overwritten: loop writes rows 1..64 only)
  if (t < 64) As[0][t] = (bf16)0.f;
  else if (t < 128) As[65][t - 64] = (bf16)0.f;

  v8bf areg[2], breg[3][2];
  loadA(0, areg);
  loadB(0, breg);

  for (int it = 0; it < 12; ++it) {
    __syncthreads();
    *(v8bf*)&As[ax + 1][ac0] = areg[0];
    *(v8bf*)&As[ax + 1][ac0 + 32] = areg[1];
#pragma unroll
    for (int d = 0; d < 3; ++d) {
      *(v8bf*)&Bs[d][bco][bk] = breg[d][0];
      *(v8bf*)&Bs[d][bco][bk + 32] = breg[d][1];
    }
    __syncthreads();
    if (it < 11) { loadA(it + 1, areg); loadB(it + 1, breg); }
#pragma unroll
    for (int d = 0; d < 3; ++d) {
#pragma unroll
      for (int ksub = 0; ksub < 2; ++ksub) {
        v8bf af0 = *(const v8bf*)&As[wr + d + l15][ksub * 32 + l4 * 8];
        v8bf af1 = *(const v8bf*)&As[wr + 16 + d + l15][ksub * 32 + l4 * 8];
#pragma unroll
        for (int j = 0; j < 2; ++j) {
          v8bf bfr = *(const v8bf*)&Bs[d][wc + j * 16 + l15][ksub * 32 + l4 * 8];
          acc[0][j] = MFMA16(af0, bfr, acc[0][j]);
          acc[1][j] = MFMA16(af1, bfr, acc[1][j]);
        }
      }
    }
  }
#pragma unroll
  for (int i = 0; i < 2; ++i) {
    int nb = y * 64 + wr + i * 16 + l4 * 4;
#pragma unroll
    for (int j = 0; j < 2; ++j) {
      int c = co0 + wc + j * 16 + l15;
      float scale = sp[c], shift = sp[128 + c];
      if (mode == 0) {
        bf16* o = (bf16*)out_ + ((long)(tsr * 2 + b) * 4096 + nb) * 128 + c;
#pragma unroll
        for (int r = 0; r < 4; ++r)
          o[r * 128] = (bf16)sf(fmaxf(acc[i][j][r] * scale + shift, 0.f));
      } else {
        v4f pk;
#pragma unroll
        for (int r = 0; r < 4; ++r)
          pk[r] = sf(fmaxf(acc[i][j][r] * scale + shift, 0.f));
        *(v4f*)((float*)out_ + ((long)b * 128 + c) * 4096 + nb) = pk;
      }
    }
  }
}

// ---------------- fused 1x1 convs; outputs stored in MFMA-fragment-major layouts ----------------
__global__ __launch_bounds__(256) void conv1_kernel(
    const bf16* __restrict__ feat_base,
    const float* __restrict__ cv_w, const float* __restrict__ k1_w, const float* __restrict__ q1_w,
    const float* __restrict__ k2_w, const float* __restrict__ q2_w,
    const float* __restrict__ cv_b, const float* __restrict__ k1_b, const float* __restrict__ q1_b,
    const float* __restrict__ k2_b, const float* __restrict__ q2_b,
    bf16* __restrict__ v_base, bf16* __restrict__ keyT, bf16* __restrict__ queryT,
    float* __restrict__ pmean)
{
  int nt = blockIdx.x;  // 0..127, 32 rows each
  int br = blockIdx.z >> 1, b = blockIdx.z & 1;
  long zid = br * 2 + b;
  const bf16* feat = feat_base + zid * 524288 + (long)nt * 4096;

  __shared__ bf16 As[32][40];
  __shared__ bf16 Bs[256][40];

  int t = threadIdx.x, lane = t & 63, w = t >> 6;
  int l15 = lane & 15, l4 = lane >> 4;
  int wr = (w & 1) * 16, wc = (w >> 1) * 128;

  const float* wrow;
  bool negk = false;
  if (t < 128)       wrow = cv_w + (long)t * 128;
  else if (t < 192) { wrow = (br ? k2_w : k1_w) + (long)(t - 128) * 128; negk = (br != 0); }
  else               wrow = (br ? q2_w : q1_w) + (long)(t - 192) * 128;

  v4f acc[8] = {};
  int ap = t >> 2, ak = (t & 3) * 8;

  for (int ks = 0; ks < 4; ++ks) {
    int ci0 = ks * 32;
    v8bf av;
    if (t < 128) av = *(const v8bf*)(feat + ap * 128 + ci0 + ak);
    float wv[32];
#pragma unroll
    for (int u = 0; u < 32; ++u) wv[u] = wrow[ci0 + u];
    if (negk) {
#pragma unroll
      for (int u = 0; u < 32; ++u) wv[u] = -wv[u];
    }
    __syncthreads();
    if (t < 128) *(v8bf*)&As[ap][ak] = av;
#pragma unroll
    for (int u = 0; u < 32; ++u) Bs[t][u] = (bf16)wv[u];
    __syncthreads();
    v8bf af = *(const v8bf*)&As[wr + l15][l4 * 8];
#pragma unroll
    for (int j = 0; j < 8; ++j) {
      v8bf bfr = *(const v8bf*)&Bs[wc + j * 16 + l15][l4 * 8];
      acc[j] = MFMA16(af, bfr, acc[j]);
    }
  }

  int nb = nt * 32 + wr + l4 * 4;
#pragma unroll
  for (int j = 0; j < 8; ++j) {
    int c = wc + j * 16 + l15;
    float bv;
    if (c < 128)      bv = cv_b[c];
    else if (c < 192) bv = br ? -k2_b[c - 128] : k1_b[c - 128];
    else              bv = (br ? q2_b : q1_b)[c - 192];
    float v0 = sf(acc[j][0] + bv), v1 = sf(acc[j][1] + bv);
    float v2 = sf(acc[j][2] + bv), v3 = sf(acc[j][3] + bv);
    if (c < 128) {
      long off = (long)(nb >> 5) * 4096 + (c >> 4) * 512 + ((nb >> 3) & 3) * 128 +
                 (c & 15) * 8 + (nb & 7);
      v4bf pk;
      pk[0] = (bf16)v0; pk[1] = (bf16)v1; pk[2] = (bf16)v2; pk[3] = (bf16)v3;
      *(v4bf*)(v_base + zid * 524288 + off) = pk;
      float s = v0 + v1 + v2 + v3;
      s += __shfl_xor(s, 16, 64);
      s += __shfl_xor(s, 32, 64);
      if (l4 == 0) atomicAdd(&pmean[zid * 128 + c], s);
    } else if (c < 192) {
      int cc = (c - 128) + br * 64;
      long off = (long)(nb >> 4) * 2048 + (cc >> 5) * 512 + ((cc >> 3) & 3) * 128 +
                 (nb & 15) * 8 + (cc & 7);
      bf16* kp = keyT + (long)b * 524288 + off;
      kp[0] = (bf16)v0; kp[8] = (bf16)v1; kp[16] = (bf16)v2; kp[24] = (bf16)v3;
    } else {
      int cc = (c - 192) + br * 64;
      long off = (long)(nb >> 4) * 2048 + (cc >> 5) * 512 + ((cc >> 3) & 3) * 128 +
                 (nb & 15) * 8 + (cc & 7);
      bf16* qp = queryT + (long)b * 524288 + off;
      qp[0] = (bf16)v0; qp[8] = (bf16)v1; qp[16] = (bf16)v2; qp[24] = (bf16)v3;
    }
  }
}

// ---------------- flash apply v10 (r10 winner): per-wave independent 32-m chunks, wave-private
// P transpose (no barrier in main loop), one post-loop LDS reduction; XCD swizzle ----
__global__ __launch_bounds__(256, 2) void apply_kernel(
    const bf16* __restrict__ keyT, const bf16* __restrict__ queryT,
    const bf16* __restrict__ v_base,
    const float* __restrict__ pmean,
    const float* __restrict__ g1_w, const float* __restrict__ g1_b,
    const float* __restrict__ g2_w, const float* __restrict__ g2_b,
    bf16* __restrict__ feat_base, float* __restrict__ d_out)
{
  int bid = blockIdx.x;
  int xcd = bid & 7;
  int z = xcd >> 1;                       // one (br,b) per XCD pair-slice
  int nt = (xcd & 1) * 64 + (bid >> 3);   // 0..127
  int br = z >> 1, b = z & 1;
  int n0 = nt * 32;
  const bf16* Xf = (br ? queryT : keyT) + (long)b * 524288 + (long)(n0 >> 4) * 2048;
  const bf16* Yf = (br ? keyT : queryT) + (long)b * 524288;
  const bf16* Vf = v_base + (long)(br * 2 + b) * 524288;
  bf16* feat = feat_base + (long)(br * 2 + b) * 524288 + (long)n0 * 128;

  // Psw (in-loop, per-wave private) and Fred (post-loop reduce) alias the same buffer.
  __shared__ __align__(16) char smem_raw[18432];   // max(4*32*40*2, 128*36*4)
  bf16 (*Psw)[32][40] = reinterpret_cast<bf16(*)[32][40]>(smem_raw);
  float (*Fred)[36] = reinterpret_cast<float(*)[36]>(smem_raw);
  __shared__ float rps[4][32];
  __shared__ float gl[128];
  __shared__ float hh[8];

  int t = threadIdx.x, lane = t & 63, w = t >> 6;
  int l15 = lane & 15, l4 = lane >> 4;

  // inline channel-gate MLP (pmean ready before this kernel launches)
  {
    const float* pm = pmean + (br * 2 + b) * 128;
    if (t < 8) {
      float a = g1_b[t];
      for (int c = 0; c < 128; ++c) a += g1_w[t * 128 + c] * (pm[c] * (1.f / 4096.f));
      hh[t] = fmaxf(a, 0.f);
    }
    __syncthreads();
    if (t < 128) {
      float a = g2_b[t];
#pragma unroll
      for (int j = 0; j < 8; ++j) a += g2_w[t * 8 + j] * hh[j];
      gl[t] = sf(1.f / (1.f + __expf(-a)));
    }
  }

  // X A-fragments (full 32 rows, shared by all waves)
  v8bf af[2][4];
#pragma unroll
  for (int i = 0; i < 2; ++i)
#pragma unroll
    for (int k = 0; k < 4; ++k)
      af[i][k] = *(const v8bf*)(Xf + i * 2048 + k * 512 + lane * 8);

  v4f acc[2][8] = {};   // [n-frag][c-frag], partial over this wave's m
  float rp[2][4] = {};

  auto loadBy = [&](int mb, v8bf (&by)[2][4]) {
    const bf16* p = Yf + (long)(mb >> 4) * 2048 + lane * 8;
#pragma unroll
    for (int mf = 0; mf < 2; ++mf)
#pragma unroll
      for (int k = 0; k < 4; ++k) by[mf][k] = *(const v8bf*)(p + mf * 2048 + k * 512);
  };

  v8bf byA[2][4], byB[2][4];
  loadBy(w * 32, byA);

  auto subiter = [&](int it, v8bf (&byC)[2][4], v8bf (&byN)[2][4]) {
    int mb = it * 128 + w * 32;
    // V B-fragments for this m-chunk: issued early, consumed at PV (latency covered by QK+exp)
    v8bf vb[8];
    {
      const bf16* p = Vf + (long)(mb >> 5) * 4096 + lane * 8;
#pragma unroll
      for (int j = 0; j < 8; ++j) vb[j] = *(const v8bf*)(p + j * 512);
    }
    // QK: S[32n][32m] for this wave's m-chunk
    v4f sacc[2][2] = {};
#pragma unroll
    for (int k = 0; k < 4; ++k)
#pragma unroll
      for (int i = 0; i < 2; ++i)
#pragma unroll
        for (int mf = 0; mf < 2; ++mf)
          sacc[i][mf] = MFMA16(af[i][k], byC[mf][k], sacc[i][mf]);
    if (it < 31) loadBy(mb + 128, byN);   // prefetch next Y chunk
    // exp + row-sum partials + wave-private P^T staging (no barrier: same-wave DS in-order)
#pragma unroll
    for (int i = 0; i < 2; ++i)
#pragma unroll
      for (int mf = 0; mf < 2; ++mf)
#pragma unroll
        for (int r = 0; r < 4; ++r) {
          float e = __expf(fminf(fabsf(sacc[i][mf][r]), 80.f) - 50.f);
          rp[i][r] += e;
          Psw[w][i * 16 + l4 * 4 + r][mf * 16 + l15] = (bf16)e;
        }
    v8bf ap0 = *(const v8bf*)&Psw[w][l15][l4 * 8];
    v8bf ap1 = *(const v8bf*)&Psw[w][16 + l15][l4 * 8];
    // PV: k=32 over this wave's 32 m; 16 independent MFMAs
#pragma unroll
    for (int j = 0; j < 8; ++j) {
      acc[0][j] = MFMA16(ap0, vb[j], acc[0][j]);
      acc[1][j] = MFMA16(ap1, vb[j], acc[1][j]);
    }
  };

  for (int it2 = 0; it2 < 16; ++it2) {
    subiter(it2 * 2, byA, byB);
    subiter(it2 * 2 + 1, byB, byA);
  }

  // per-wave denominator partials (sum over this wave's m via l15 butterfly)
#pragma unroll
  for (int i = 0; i < 2; ++i)
#pragma unroll
    for (int r = 0; r < 4; ++r) {
      float v = rp[i][r];
      v += __shfl_xor(v, 1, 64);
      v += __shfl_xor(v, 2, 64);
      v += __shfl_xor(v, 4, 64);
      v += __shfl_xor(v, 8, 64);
      if (l15 == 0) rps[w][i * 16 + l4 * 4 + r] = v;
    }
  __syncthreads();   // all waves done with Psw reads + rps written

  // cross-wave numerator reduction into Fred[c][n] (aliases Psw; protected by barrier above)
#pragma unroll
  for (int ww = 0; ww < 4; ++ww) {
    if (w == ww) {
#pragma unroll
      for (int i = 0; i < 2; ++i)
#pragma unroll
        for (int j = 0; j < 8; ++j) {
          float* fp = &Fred[j * 16 + l15][i * 16 + l4 * 4];
          if (ww == 0) *(v4f*)fp = acc[i][j];
          else {
            v4f old = *(v4f*)fp;
#pragma unroll
            for (int r = 0; r < 4; ++r) old[r] += acc[i][j][r];
            *(v4f*)fp = old;
          }
        }
    }
    __syncthreads();
  }

  // epilogue: divide, gate, residual; fp32 E to d_out + bf16 E in-place over feat
  float* outE = d_out + (long)(br ? 1 : 2) * 1048576 + (long)b * 524288;
  int wr = (w & 1) * 16, wc = (w >> 1) * 64;
  int rowt = wr + l4 * 4;
  float dv[4];
#pragma unroll
  for (int r = 0; r < 4; ++r)
    dv[r] = fmaxf(rps[0][rowt + r] + rps[1][rowt + r] + rps[2][rowt + r] + rps[3][rowt + r],
                  1e-30f);
#pragma unroll
  for (int j = 0; j < 4; ++j) {
    int c = wc + j * 16 + l15;
    float g = gl[c];
    v4f nm = *(const v4f*)&Fred[c][rowt];
    v4f pk;
#pragma unroll
    for (int r = 0; r < 4; ++r) {
      long fi = (long)(rowt + r) * 128 + c;
      float fv = (float)feat[fi];
      float val = sf(nm[r] / dv[r] * g + fv);
      pk[r] = val;
      feat[fi] = (bf16)val;   // in-place bf16 E for conv_cat (same thread read->write)
    }
    *(v4f*)(outE + (long)c * 4096 + n0 + rowt) = pk;
  }
}

// ---------------- launch ----------------
extern "C" void kernel_launch(void* const* d_in, const int* in_sizes, int n_in,
                              void* d_out, int out_size, void* d_ws, size_t ws_size,
                              hipStream_t stream)
{
  if (n_in != 33 || in_sizes[0] != 2097152 || in_sizes[2] != 294912 ||
      in_sizes[14] != 16384 || out_size != 3145728) {
    fill_kernel<<<12288, 256, 0, stream>>>((float*)d_out, 100.0f, 3145728);
    return;
  }
  if (ws_size < 12582912) {
    fill_kernel<<<12288, 256, 0, stream>>>((float*)d_out, 1.0f, 3145728);
    return;
  }

  const float* q_in = (const float*)d_in[0];
  const float* s_in = (const float*)d_in[1];
  char* ob = (char*)d_out;
  float* outf = (float*)d_out;

  float* pmean = (float*)(ob + 0);        // [4][128] f32 (atomic partial sums)
  bf16*  xin   = (bf16*)(ob + 4194304);   // [4][4096][256] bf16 NHWC

  char* ws = (char*)d_ws;
  bf16*  sfeat  = (bf16*)(ws + 0);         // [4][4096][128] bf16 (E bf16 in-place after apply)
  bf16*  vs     = (bf16*)(ws + 4194304);   // [4] frag-major V
  bf16*  keyT   = (bf16*)(ws + 8388608);   // [2] frag-major key
  bf16*  queryT = (bf16*)(ws + 10485760);  // [2] frag-major query
  bf16*  Wt01   = (bf16*)(ws + 8388608);   // alias: dead before conv1 writes keyT
  float* ss01   = (float*)(ws + 10485760); // alias: dead before conv1 writes queryT

  bool room = ws_size >= (size_t)13173760;
  bf16*  Wt2   = room ? (bf16*)(ws + 12582912) : (bf16*)(ws + 8388608);
  float* ss_cc = room ? (float*)(ws + 13172736) : (float*)(ws + 8978432);

  prep_all_kernel<<<room ? 3716 : 2563, 256, 0, stream>>>(
      s_in, q_in, xin,
      (const float*)d_in[2], (const float*)d_in[8],
      (const float*)d_in[3], (const float*)d_in[4], (const float*)d_in[5],
      (const float*)d_in[6], (const float*)d_in[7],
      (const float*)d_in[9], (const float*)d_in[10], (const float*)d_in[11],
      (const float*)d_in[12], (const float*)d_in[13],
      Wt01, ss01, pmean,
      (const float*)d_in[28], (const float*)d_in[29], (const float*)d_in[30],
      (const float*)d_in[31], (const float*)d_in[32],
      Wt2, ss_cc, room ? 1 : 0);

  convN_kernel<<<512, 256, 0, stream>>>(xin, Wt01, ss01, sfeat, 0);

  conv1_kernel<<<dim3(128, 1, 4), 256, 0, stream>>>(
      sfeat,
      (const float*)d_in[14], (const float*)d_in[16], (const float*)d_in[18],
      (const float*)d_in[20], (const float*)d_in[22],
      (const float*)d_in[15], (const float*)d_in[17], (const float*)d_in[19],
      (const float*)d_in[21], (const float*)d_in[23],
      vs, keyT, queryT, pmean);

  apply_kernel<<<512, 256, 0, stream>>>(
      keyT, queryT, vs, pmean,
      (const float*)d_in[24], (const float*)d_in[25],
      (const float*)d_in[26], (const float*)d_in[27],
      sfeat, outf);

  if (!room) {
    prep2_kernel<<<1153, 256, 0, stream>>>(
        (const float*)d_in[28], (const float*)d_in[29], (const float*)d_in[30],
        (const float*)d_in[31], (const float*)d_in[32], Wt2, ss_cc);
  }

  convN_kernel<<<256, 256, 0, stream>>>(sfeat, Wt2, ss_cc, outf, 1);
}

// Round 14
// 244.313 us; speedup vs baseline: 1.9101x; 1.0188x over previous
//
#include <hip/hip_runtime.h>

typedef __bf16 bf16;
typedef __bf16 v8bf __attribute__((ext_vector_type(8)));
typedef __bf16 v4bf __attribute__((ext_vector_type(4)));
typedef float v4f __attribute__((ext_vector_type(4)));

#define MFMA16(a, b, c) __builtin_amdgcn_mfma_f32_16x16x32_bf16(a, b, c, 0, 0, 0)

// NaN -> 0, clamp +-1e30. Insurance only.
__device__ __forceinline__ float sf(float x) {
  if (!(x == x)) return 0.f;
  return fminf(fmaxf(x, -1e30f), 1e30f);
}

// ---------------- guard fill (fp32 out) ----------------
__global__ __launch_bounds__(256) void fill_kernel(float* __restrict__ out, float v, int n) {
  int i = blockIdx.x * 256 + threadIdx.x;
  if (i < n) out[i] = v;
}

// ---------------- prep_all: tr (blocks 0..255) + stem weight prep + pmean zero
//   + conv1 weight frag-major preconvert (2 variants) + optional conv_cat prep ----------------
__global__ __launch_bounds__(256) void prep_all_kernel(
    const float* __restrict__ s_in, const float* __restrict__ q_in, bf16* __restrict__ xin,
    const float* __restrict__ ts_w, const float* __restrict__ tq_w,
    const float* ts_b, const float* ts_g, const float* ts_be, const float* ts_m, const float* ts_v,
    const float* tq_b, const float* tq_g, const float* tq_be, const float* tq_m, const float* tq_v,
    bf16* __restrict__ Wt01, float* __restrict__ ss01, float* __restrict__ pmean,
    const float* __restrict__ cv_w, const float* __restrict__ k1_w, const float* __restrict__ q1_w,
    const float* __restrict__ k2_w, const float* __restrict__ q2_w, bf16* __restrict__ wfrag,
    const float* __restrict__ cc_w, const float* cc_g, const float* cc_be,
    const float* cc_m, const float* cc_v,
    bf16* __restrict__ Wt2, float* __restrict__ ss_cc, int do_prep2)
{
  int bx = blockIdx.x, t = threadIdx.x;
  if (bx < 256) {
    // NCHW fp32 -> NHWC bf16 transpose (coalesced reads along n)
    int nb = bx & 63, z = bx >> 6;
    const float* in = ((z >> 1) ? q_in : s_in) + (long)(z & 1) * 1048576;
    bf16* out = xin + (long)z * 1048576;
    int lane = t & 63, w = t >> 6;
    long n = (long)nb * 64 + lane;
#pragma unroll
    for (int i = 0; i < 8; ++i) {
      int c8 = w * 8 + i;
      v8bf o;
#pragma unroll
      for (int j = 0; j < 8; ++j) o[j] = (bf16)in[(long)(c8 * 8 + j) * 4096 + n];
      *(v8bf*)(out + n * 256 + c8 * 8) = o;
    }
    return;
  }
  int idx = (bx - 256) * 256 + t;
  if (idx < 589824) {
    int which = idx / 294912;
    int rem = idx - which * 294912;
    int co = rem / 2304;
    int r2 = rem - co * 2304;
    int tap = r2 >> 8;
    int ci = r2 & 255;
    const float* W = which ? tq_w : ts_w;
    Wt01[idx] = (bf16)W[(co * 256 + ci) * 9 + tap];
  } else if (idx < 590080) {
    int i = idx - 589824;
    int which = i >> 7, c = i & 127;
    float g, be, m, vv, bias;
    if (which == 0) { g=ts_g[c]; be=ts_be[c]; m=ts_m[c]; vv=ts_v[c]; bias=ts_b[c]; }
    else            { g=tq_g[c]; be=tq_be[c]; m=tq_m[c]; vv=tq_v[c]; bias=tq_b[c]; }
    float scale = g / sqrtf(vv + 1e-5f);
    ss01[which * 256 + c] = sf(scale);
    ss01[which * 256 + 128 + c] = sf((bias - m) * scale + be);
  } else if (idx < 590592) {
    pmean[idx - 590080] = 0.f;
  } else if (idx < 656128) {
    // conv1 weights -> frag-major bf16; variant 0: [cv,k1,q1], variant 1: [cv,-k2,q2]
    int idx2 = idx - 590592;
    int vr = idx2 >> 15;
    int rem = idx2 & 32767;
    int co = rem >> 7, K = rem & 127;
    float v;
    if (co < 128)      v = cv_w[co * 128 + K];
    else if (co < 192) v = vr ? -k2_w[(co - 128) * 128 + K] : k1_w[(co - 128) * 128 + K];
    else               v = vr ? q2_w[(co - 192) * 128 + K] : q1_w[(co - 192) * 128 + K];
    long addr = (long)vr * 32768 + (co >> 4) * 2048 + (K >> 5) * 512 + ((K >> 3) & 3) * 128 +
                (co & 15) * 8 + (K & 7);
    wfrag[addr] = (bf16)v;
  } else if (do_prep2) {
    int idx2 = idx - 656128;
    if (idx2 < 294912) {
      int co = idx2 / 2304;
      int r2 = idx2 - co * 2304;
      int tap = r2 >> 8;
      int ci = r2 & 255;
      Wt2[idx2] = (bf16)cc_w[(co * 256 + ci) * 9 + tap];
    } else if (idx2 < 295040) {
      int c = idx2 - 294912;
      float scale = cc_g[c] / sqrtf(cc_v[c] + 1e-5f);
      ss_cc[c] = sf(scale);
      ss_cc[128 + c] = sf(-cc_m[c] * scale + cc_be[c]);
    }
  }
}

// ---------------- prep2 fallback (after apply; over dead keyT) ----------------
__global__ __launch_bounds__(256) void prep2_kernel(
    const float* __restrict__ cc_w, const float* cc_g, const float* cc_be,
    const float* cc_m, const float* cc_v,
    bf16* __restrict__ Wt2, float* __restrict__ ss_cc)
{
  int idx = blockIdx.x * 256 + threadIdx.x;
  if (idx < 294912) {
    int co = idx / 2304;
    int r2 = idx - co * 2304;
    int tap = r2 >> 8;
    int ci = r2 & 255;
    Wt2[idx] = (bf16)cc_w[(co * 256 + ci) * 9 + tap];
  } else if (idx < 295040) {
    int c = idx - 294912;
    float scale = cc_g[c] / sqrtf(cc_v[c] + 1e-5f);
    ss_cc[c] = sf(scale);
    ss_cc[128 + c] = sf(-cc_m[c] * scale + cc_be[c]);
  }
}

// ---------------- 3x3 conv implicit GEMM over NHWC bf16 input, coalesced A staging;
// XCD-swizzled flat grid (r10 form) ----------
__global__ __launch_bounds__(256) void convN_kernel(
    const bf16* __restrict__ inA,
    const bf16* __restrict__ Wb, const float* __restrict__ ssb,
    void* __restrict__ out_, int mode)
{
  __shared__ bf16 As[66][40];
  __shared__ bf16 Bs[3][64][40];

  int bid = blockIdx.x;
  int xcd = bid & 7, slot = bid >> 3;
  int y, co0, tsr, b;
  if (mode == 0) {
    int z = xcd >> 1;
    tsr = z >> 1; b = z & 1;
    co0 = (xcd & 1) * 64;
    y = slot;
  } else {
    int combo = xcd >> 1;
    co0 = (combo >> 1) * 64;
    b = combo & 1;
    tsr = 0;
    y = (xcd & 1) * 32 + slot;
  }

  const bf16 *in0, *in1;
  const bf16* W;
  const float* sp;
  if (mode == 0) {
    in0 = inA + (long)(tsr * 2 + b) * 1048576;  // [4096][256]
    in1 = nullptr;
    W = Wb + (long)tsr * 294912;
    sp = ssb + tsr * 256;
  } else {
    in0 = inA + (long)(2 + b) * 524288; // E_q bf16 [4096][128]
    in1 = inA + (long)b * 524288;       // E_s bf16 [4096][128]
    W = Wb; sp = ssb;
  }

  int t = threadIdx.x, lane = t & 63, w = t >> 6;
  int l15 = lane & 15, l4 = lane >> 4;
  int wr = (w & 1) * 32, wc = (w >> 1) * 32;
  int ax = t >> 2, ac0 = (t & 3) * 8;
  int bco = t >> 2, bk = (t & 3) * 8;

  v4f acc[2][2] = {};

  auto loadA = [&](int it, v8bf& areg) {
    int dy = it >> 3, ks = it & 7;
    int ysrc = y + dy - 1;
    if ((unsigned)ysrc < 64u) {
      long n = (long)ysrc * 64 + ax;
      int cg = ks * 32 + ac0;
      const bf16* src;
      if (mode == 0)     src = in0 + n * 256 + cg;
      else if (cg < 128) src = in0 + n * 128 + cg;
      else               src = in1 + n * 128 + (cg - 128);
      areg = *(const v8bf*)src;
    } else {
#pragma unroll
      for (int i = 0; i < 8; ++i) areg[i] = (bf16)0.f;
    }
  };
  auto loadB = [&](int it, v8bf* breg) {
    int dy = it >> 3, ks = it & 7;
    const bf16* wk = W + (long)(co0 + bco) * 2304 + dy * 3 * 256 + ks * 32 + bk;
#pragma unroll
    for (int d = 0; d < 3; ++d) breg[d] = *(const v8bf*)(wk + d * 256);
  };

  // zero halo columns once (never overwritten: loop writes rows 1..64 only)
  if (t < 32) As[0][t] = (bf16)0.f;
  else if (t < 64) As[65][t - 32] = (bf16)0.f;

  v8bf areg, breg[3];
  loadA(0, areg);
  loadB(0, breg);

  for (int it = 0; it < 24; ++it) {
    __syncthreads();
    *(v8bf*)&As[ax + 1][ac0] = areg;
#pragma unroll
    for (int d = 0; d < 3; ++d) *(v8bf*)&Bs[d][bco][bk] = breg[d];
    __syncthreads();
    if (it < 23) { loadA(it + 1, areg); loadB(it + 1, breg); }
#pragma unroll
    for (int d = 0; d < 3; ++d) {
      v8bf af0 = *(const v8bf*)&As[wr + d + l15][l4 * 8];
      v8bf af1 = *(const v8bf*)&As[wr + 16 + d + l15][l4 * 8];
#pragma unroll
      for (int j = 0; j < 2; ++j) {
        v8bf bfr = *(const v8bf*)&Bs[d][wc + j * 16 + l15][l4 * 8];
        acc[0][j] = MFMA16(af0, bfr, acc[0][j]);
        acc[1][j] = MFMA16(af1, bfr, acc[1][j]);
      }
    }
  }
#pragma unroll
  for (int i = 0; i < 2; ++i) {
    int nb = y * 64 + wr + i * 16 + l4 * 4;
#pragma unroll
    for (int j = 0; j < 2; ++j) {
      int c = co0 + wc + j * 16 + l15;
      float scale = sp[c], shift = sp[128 + c];
      if (mode == 0) {
        bf16* o = (bf16*)out_ + ((long)(tsr * 2 + b) * 4096 + nb) * 128 + c;
#pragma unroll
        for (int r = 0; r < 4; ++r)
          o[r * 128] = (bf16)sf(fmaxf(acc[i][j][r] * scale + shift, 0.f));
      } else {
        v4f pk;
#pragma unroll
        for (int r = 0; r < 4; ++r)
          pk[r] = sf(fmaxf(acc[i][j][r] * scale + shift, 0.f));
        *(v4f*)((float*)out_ + ((long)b * 128 + c) * 4096 + nb) = pk;
      }
    }
  }
}

// ---------------- fused 1x1 convs v2: frag-major preconverted weights read direct from
// global (L2-hot), feat staged once, ONE barrier; outputs frag-major as before ----------------
__global__ __launch_bounds__(256) void conv1_kernel(
    const bf16* __restrict__ feat_base, const bf16* __restrict__ wfrag,
    const float* __restrict__ cv_b, const float* __restrict__ k1_b, const float* __restrict__ q1_b,
    const float* __restrict__ k2_b, const float* __restrict__ q2_b,
    bf16* __restrict__ v_base, bf16* __restrict__ keyT, bf16* __restrict__ queryT,
    float* __restrict__ pmean)
{
  int nt = blockIdx.x;  // 0..127, 32 rows each
  int br = blockIdx.z >> 1, b = blockIdx.z & 1;
  long zid = br * 2 + b;
  const bf16* feat = feat_base + zid * 524288 + (long)nt * 4096;
  const bf16* wf = wfrag + (long)br * 32768;

  __shared__ bf16 As[32][136];   // stride 68 dw, gcd(68,32)=4 -> 2-way max (free)

  int t = threadIdx.x, lane = t & 63, w = t >> 6;
  int l15 = lane & 15, l4 = lane >> 4;
  int wr = (w & 1) * 16, wc = (w >> 1) * 128;

  // stage feat tile (32 n x 128 c), coalesced 32B/thread
  {
    int row = t >> 3, col = (t & 7) * 16;
    *(v8bf*)&As[row][col] = *(const v8bf*)(feat + (long)row * 128 + col);
    *(v8bf*)&As[row][col + 8] = *(const v8bf*)(feat + (long)row * 128 + col + 8);
  }
  __syncthreads();

  v4f acc[8] = {};
#pragma unroll
  for (int ks = 0; ks < 4; ++ks) {
    v8bf af = *(const v8bf*)&As[wr + l15][ks * 32 + l4 * 8];
#pragma unroll
    for (int j = 0; j < 8; ++j) {
      int cog = (wc >> 4) + j;
      v8bf bfr = *(const v8bf*)(wf + (long)cog * 2048 + ks * 512 + l4 * 128 + l15 * 8);
      acc[j] = MFMA16(af, bfr, acc[j]);
    }
  }

  int nb = nt * 32 + wr + l4 * 4;
#pragma unroll
  for (int j = 0; j < 8; ++j) {
    int c = wc + j * 16 + l15;
    float bv;
    if (c < 128)      bv = cv_b[c];
    else if (c < 192) bv = br ? -k2_b[c - 128] : k1_b[c - 128];
    else              bv = (br ? q2_b : q1_b)[c - 192];
    float v0 = sf(acc[j][0] + bv), v1 = sf(acc[j][1] + bv);
    float v2 = sf(acc[j][2] + bv), v3 = sf(acc[j][3] + bv);
    if (c < 128) {
      long off = (long)(nb >> 5) * 4096 + (c >> 4) * 512 + ((nb >> 3) & 3) * 128 +
                 (c & 15) * 8 + (nb & 7);
      v4bf pk;
      pk[0] = (bf16)v0; pk[1] = (bf16)v1; pk[2] = (bf16)v2; pk[3] = (bf16)v3;
      *(v4bf*)(v_base + zid * 524288 + off) = pk;
      float s = v0 + v1 + v2 + v3;
      s += __shfl_xor(s, 16, 64);
      s += __shfl_xor(s, 32, 64);
      if (l4 == 0) atomicAdd(&pmean[zid * 128 + c], s);
    } else if (c < 192) {
      int cc = (c - 128) + br * 64;
      long off = (long)(nb >> 4) * 2048 + (cc >> 5) * 512 + ((cc >> 3) & 3) * 128 +
                 (nb & 15) * 8 + (cc & 7);
      bf16* kp = keyT + (long)b * 524288 + off;
      kp[0] = (bf16)v0; kp[8] = (bf16)v1; kp[16] = (bf16)v2; kp[24] = (bf16)v3;
    } else {
      int cc = (c - 192) + br * 64;
      long off = (long)(nb >> 4) * 2048 + (cc >> 5) * 512 + ((cc >> 3) & 3) * 128 +
                 (nb & 15) * 8 + (cc & 7);
      bf16* qp = queryT + (long)b * 524288 + off;
      qp[0] = (bf16)v0; qp[8] = (bf16)v1; qp[16] = (bf16)v2; qp[24] = (bf16)v3;
    }
  }
}

// ---------------- flash apply v10 (r10/r13 winner): per-wave independent 32-m chunks,
// wave-private P transpose (no barrier in main loop), one post-loop LDS reduction ----
__global__ __launch_bounds__(256, 2) void apply_kernel(
    const bf16* __restrict__ keyT, const bf16* __restrict__ queryT,
    const bf16* __restrict__ v_base,
    const float* __restrict__ pmean,
    const float* __restrict__ g1_w, const float* __restrict__ g1_b,
    const float* __restrict__ g2_w, const float* __restrict__ g2_b,
    bf16* __restrict__ feat_base, float* __restrict__ d_out)
{
  int bid = blockIdx.x;
  int xcd = bid & 7;
  int z = xcd >> 1;                       // one (br,b) per XCD pair-slice
  int nt = (xcd & 1) * 64 + (bid >> 3);   // 0..127
  int br = z >> 1, b = z & 1;
  int n0 = nt * 32;
  const bf16* Xf = (br ? queryT : keyT) + (long)b * 524288 + (long)(n0 >> 4) * 2048;
  const bf16* Yf = (br ? keyT : queryT) + (long)b * 524288;
  const bf16* Vf = v_base + (long)(br * 2 + b) * 524288;
  bf16* feat = feat_base + (long)(br * 2 + b) * 524288 + (long)n0 * 128;

  // Psw (in-loop, per-wave private) and Fred (post-loop reduce) alias the same buffer.
  __shared__ __align__(16) char smem_raw[18432];   // max(4*32*40*2, 128*36*4)
  bf16 (*Psw)[32][40] = reinterpret_cast<bf16(*)[32][40]>(smem_raw);
  float (*Fred)[36] = reinterpret_cast<float(*)[36]>(smem_raw);
  __shared__ float rps[4][32];
  __shared__ float gl[128];
  __shared__ float hh[8];

  int t = threadIdx.x, lane = t & 63, w = t >> 6;
  int l15 = lane & 15, l4 = lane >> 4;

  // inline channel-gate MLP (pmean ready before this kernel launches)
  {
    const float* pm = pmean + (br * 2 + b) * 128;
    if (t < 8) {
      float a = g1_b[t];
      for (int c = 0; c < 128; ++c) a += g1_w[t * 128 + c] * (pm[c] * (1.f / 4096.f));
      hh[t] = fmaxf(a, 0.f);
    }
    __syncthreads();
    if (t < 128) {
      float a = g2_b[t];
#pragma unroll
      for (int j = 0; j < 8; ++j) a += g2_w[t * 8 + j] * hh[j];
      gl[t] = sf(1.f / (1.f + __expf(-a)));
    }
  }

  // X A-fragments (full 32 rows, shared by all waves)
  v8bf af[2][4];
#pragma unroll
  for (int i = 0; i < 2; ++i)
#pragma unroll
    for (int k = 0; k < 4; ++k)
      af[i][k] = *(const v8bf*)(Xf + i * 2048 + k * 512 + lane * 8);

  v4f acc[2][8] = {};   // [n-frag][c-frag], partial over this wave's m
  float rp[2][4] = {};

  auto loadBy = [&](int mb, v8bf (&by)[2][4]) {
    const bf16* p = Yf + (long)(mb >> 4) * 2048 + lane * 8;
#pragma unroll
    for (int mf = 0; mf < 2; ++mf)
#pragma unroll
      for (int k = 0; k < 4; ++k) by[mf][k] = *(const v8bf*)(p + mf * 2048 + k * 512);
  };

  v8bf byA[2][4], byB[2][4];
  loadBy(w * 32, byA);

  auto subiter = [&](int it, v8bf (&byC)[2][4], v8bf (&byN)[2][4]) {
    int mb = it * 128 + w * 32;
    // V B-fragments for this m-chunk: issued early, consumed at PV (latency covered by QK+exp)
    v8bf vb[8];
    {
      const bf16* p = Vf + (long)(mb >> 5) * 4096 + lane * 8;
#pragma unroll
      for (int j = 0; j < 8; ++j) vb[j] = *(const v8bf*)(p + j * 512);
    }
    // QK: S[32n][32m] for this wave's m-chunk
    v4f sacc[2][2] = {};
#pragma unroll
    for (int k = 0; k < 4; ++k)
#pragma unroll
      for (int i = 0; i < 2; ++i)
#pragma unroll
        for (int mf = 0; mf < 2; ++mf)
          sacc[i][mf] = MFMA16(af[i][k], byC[mf][k], sacc[i][mf]);
    if (it < 31) loadBy(mb + 128, byN);   // prefetch next Y chunk
    // exp + row-sum partials + wave-private P^T staging (no barrier: same-wave DS in-order)
#pragma unroll
    for (int i = 0; i < 2; ++i)
#pragma unroll
      for (int mf = 0; mf < 2; ++mf)
#pragma unroll
        for (int r = 0; r < 4; ++r) {
          float e = __expf(fminf(fabsf(sacc[i][mf][r]), 80.f) - 50.f);
          rp[i][r] += e;
          Psw[w][i * 16 + l4 * 4 + r][mf * 16 + l15] = (bf16)e;
        }
    v8bf ap0 = *(const v8bf*)&Psw[w][l15][l4 * 8];
    v8bf ap1 = *(const v8bf*)&Psw[w][16 + l15][l4 * 8];
    // PV: k=32 over this wave's 32 m; 16 independent MFMAs
#pragma unroll
    for (int j = 0; j < 8; ++j) {
      acc[0][j] = MFMA16(ap0, vb[j], acc[0][j]);
      acc[1][j] = MFMA16(ap1, vb[j], acc[1][j]);
    }
  };

  for (int it2 = 0; it2 < 16; ++it2) {
    subiter(it2 * 2, byA, byB);
    subiter(it2 * 2 + 1, byB, byA);
  }

  // per-wave denominator partials (sum over this wave's m via l15 butterfly)
#pragma unroll
  for (int i = 0; i < 2; ++i)
#pragma unroll
    for (int r = 0; r < 4; ++r) {
      float v = rp[i][r];
      v += __shfl_xor(v, 1, 64);
      v += __shfl_xor(v, 2, 64);
      v += __shfl_xor(v, 4, 64);
      v += __shfl_xor(v, 8, 64);
      if (l15 == 0) rps[w][i * 16 + l4 * 4 + r] = v;
    }
  __syncthreads();   // all waves done with Psw reads + rps written

  // cross-wave numerator reduction into Fred[c][n] (aliases Psw; protected by barrier above)
#pragma unroll
  for (int ww = 0; ww < 4; ++ww) {
    if (w == ww) {
#pragma unroll
      for (int i = 0; i < 2; ++i)
#pragma unroll
        for (int j = 0; j < 8; ++j) {
          float* fp = &Fred[j * 16 + l15][i * 16 + l4 * 4];
          if (ww == 0) *(v4f*)fp = acc[i][j];
          else {
            v4f old = *(v4f*)fp;
#pragma unroll
            for (int r = 0; r < 4; ++r) old[r] += acc[i][j][r];
            *(v4f*)fp = old;
          }
        }
    }
    __syncthreads();
  }

  // epilogue: divide, gate, residual; fp32 E to d_out + bf16 E in-place over feat
  float* outE = d_out + (long)(br ? 1 : 2) * 1048576 + (long)b * 524288;
  int wr = (w & 1) * 16, wc = (w >> 1) * 64;
  int rowt = wr + l4 * 4;
  float dv[4];
#pragma unroll
  for (int r = 0; r < 4; ++r)
    dv[r] = fmaxf(rps[0][rowt + r] + rps[1][rowt + r] + rps[2][rowt + r] + rps[3][rowt + r],
                  1e-30f);
#pragma unroll
  for (int j = 0; j < 4; ++j) {
    int c = wc + j * 16 + l15;
    float g = gl[c];
    v4f nm = *(const v4f*)&Fred[c][rowt];
    v4f pk;
#pragma unroll
    for (int r = 0; r < 4; ++r) {
      long fi = (long)(rowt + r) * 128 + c;
      float fv = (float)feat[fi];
      float val = sf(nm[r] / dv[r] * g + fv);
      pk[r] = val;
      feat[fi] = (bf16)val;   // in-place bf16 E for conv_cat (same thread read->write)
    }
    *(v4f*)(outE + (long)c * 4096 + n0 + rowt) = pk;
  }
}

// ---------------- launch ----------------
extern "C" void kernel_launch(void* const* d_in, const int* in_sizes, int n_in,
                              void* d_out, int out_size, void* d_ws, size_t ws_size,
                              hipStream_t stream)
{
  if (n_in != 33 || in_sizes[0] != 2097152 || in_sizes[2] != 294912 ||
      in_sizes[14] != 16384 || out_size != 3145728) {
    fill_kernel<<<12288, 256, 0, stream>>>((float*)d_out, 100.0f, 3145728);
    return;
  }
  if (ws_size < 12582912) {
    fill_kernel<<<12288, 256, 0, stream>>>((float*)d_out, 1.0f, 3145728);
    return;
  }

  const float* q_in = (const float*)d_in[0];
  const float* s_in = (const float*)d_in[1];
  char* ob = (char*)d_out;
  float* outf = (float*)d_out;

  // d_out scratch: pmean (2KB at ob+0), wfrag (131KB at ob+64K; dead until convN1 epilogue),
  //                xin (8 MB in slots 1-2; dead after convN0, then final E_q/E_s)
  float* pmean = (float*)(ob + 0);        // [4][128] f32 (atomic partial sums)
  bf16*  wfrag = (bf16*)(ob + 65536);     // [2][256][128] frag-major conv1 weights
  bf16*  xin   = (bf16*)(ob + 4194304);   // [4][4096][256] bf16 NHWC

  char* ws = (char*)d_ws;
  bf16*  sfeat  = (bf16*)(ws + 0);         // [4][4096][128] bf16 (E bf16 in-place after apply)
  bf16*  vs     = (bf16*)(ws + 4194304);   // [4] frag-major V
  bf16*  keyT   = (bf16*)(ws + 8388608);   // [2] frag-major key
  bf16*  queryT = (bf16*)(ws + 10485760);  // [2] frag-major query
  bf16*  Wt01   = (bf16*)(ws + 8388608);   // alias: dead before conv1 writes keyT
  float* ss01   = (float*)(ws + 10485760); // alias: dead before conv1 writes queryT

  bool room = ws_size >= (size_t)13173760;
  bf16*  Wt2   = room ? (bf16*)(ws + 12582912) : (bf16*)(ws + 8388608);
  float* ss_cc = room ? (float*)(ws + 13172736) : (float*)(ws + 8978432);

  prep_all_kernel<<<room ? 3972 : 2819, 256, 0, stream>>>(
      s_in, q_in, xin,
      (const float*)d_in[2], (const float*)d_in[8],
      (const float*)d_in[3], (const float*)d_in[4], (const float*)d_in[5],
      (const float*)d_in[6], (const float*)d_in[7],
      (const float*)d_in[9], (const float*)d_in[10], (const float*)d_in[11],
      (const float*)d_in[12], (const float*)d_in[13],
      Wt01, ss01, pmean,
      (const float*)d_in[14], (const float*)d_in[16], (const float*)d_in[18],
      (const float*)d_in[20], (const float*)d_in[22], wfrag,
      (const float*)d_in[28], (const float*)d_in[29], (const float*)d_in[30],
      (const float*)d_in[31], (const float*)d_in[32],
      Wt2, ss_cc, room ? 1 : 0);

  convN_kernel<<<512, 256, 0, stream>>>(xin, Wt01, ss01, sfeat, 0);

  conv1_kernel<<<dim3(128, 1, 4), 256, 0, stream>>>(
      sfeat, wfrag,
      (const float*)d_in[15], (const float*)d_in[17], (const float*)d_in[19],
      (const float*)d_in[21], (const float*)d_in[23],
      vs, keyT, queryT, pmean);

  apply_kernel<<<512, 256, 0, stream>>>(
      keyT, queryT, vs, pmean,
      (const float*)d_in[24], (const float*)d_in[25],
      (const float*)d_in[26], (const float*)d_in[27],
      sfeat, outf);

  if (!room) {
    prep2_kernel<<<1153, 256, 0, stream>>>(
        (const float*)d_in[28], (const float*)d_in[29], (const float*)d_in[30],
        (const float*)d_in[31], (const float*)d_in[32], Wt2, ss_cc);
  }

  convN_kernel<<<256, 256, 0, stream>>>(sfeat, Wt2, ss_cc, outf, 1);
}